// Round 11
// baseline (9919.028 us; speedup 1.0000x reference)
//
#include <hip/hip_runtime.h>

// ============================================================================
// BiLSTM + CRF Viterbi.  Round 11: DIAGNOSTIC round.
//  Real pipeline = R10 exactly (unchanged, correct output).  After viterbi,
//  three scratch-only lstm_diag dispatches ablate the persist kernel:
//    mode 0: identical step loop (calibration)
//    mode 1: no sync (no drain/S2/flag/poll/S0) -> isolates sync+IF$ chain
//    mode 2: no sync + no fA loads               -> isolates h-read cost
//  They write only to already-consumed scratch (outbf/Cst/Hst/hx); d_out is
//  produced before they run -> correctness & determinism preserved.
// ============================================================================

#define B_ 64
#define T_ 512
#define NT_ 24

typedef __attribute__((ext_vector_type(8))) short bf16x8;
typedef __attribute__((ext_vector_type(4))) float f32x4;
typedef __attribute__((ext_vector_type(4))) unsigned int u32x4;

#define MFMA16(a, b, c) __builtin_amdgcn_mfma_f32_16x16x32_bf16(a, b, c, 0, 0, 0)

__device__ __forceinline__ unsigned short f2bf(float x) {
  unsigned u = __float_as_uint(x);
  u += 0x7FFFu + ((u >> 16) & 1u);
  return (unsigned short)(u >> 16);
}
__device__ __forceinline__ float bf2f(unsigned short h) {
  return __uint_as_float(((unsigned)h) << 16);
}

// ---------------- ws layout (bytes) ----------------
#define O_WHHB  ((size_t)0)
#define O_WIHB  ((size_t)4194304)
#define O_XB    ((size_t)8388608)
#define O_OUT   ((size_t)41943040)
#define SZ_OUT  ((size_t)67108864)
#define O_HX    ((size_t)109051904)
#define SZ_HX   ((size_t)262144)
#define O_HF    ((size_t)109314048)
#define O_CF    ((size_t)109576192)
#define O_EMIS  ((size_t)109838336)
#define O_BAR   ((size_t)112984064)
#define O_XP    ((size_t)112986112)

// ---------------- fp32 -> bf16 cast ----------------
__global__ void cast_bf(const float* __restrict__ src,
                        unsigned short* __restrict__ dst, int n) {
  int i = (blockIdx.x * blockDim.x + threadIdx.x) * 4;
  int stride = gridDim.x * blockDim.x * 4;
  for (; i < n; i += stride) {
    float4 v = *(const float4*)(src + i);
    ushort4 o;
    o.x = f2bf(v.x); o.y = f2bf(v.y); o.z = f2bf(v.z); o.w = f2bf(v.w);
    *(ushort4*)(dst + i) = o;
  }
}

// ---------------- xp GEMM (R10, unchanged) ----------------
__global__ __launch_bounds__(256) void xp_gemm(
    const unsigned short* __restrict__ xb,
    const unsigned short* __restrict__ wih,
    const float* __restrict__ bias_f, const float* __restrict__ bias_b,
    const int* __restrict__ length,
    unsigned short* __restrict__ xp, int t0, int Tc) {
  __shared__ char smem[32768];
  __shared__ int rowoff[128];
  const int tid = threadIdx.x;
  const int dir = blockIdx.z;
  const int m0 = blockIdx.x * 128;
  const int n0 = blockIdx.y * 128;
  if (tid < 128) {
    int m = m0 + tid;
    int tt = t0 + (m >> 6);
    int b = m & 63;
    int st = tt;
    if (dir) { st = length[b] - 1 - tt; st = st < 0 ? 0 : (st > 511 ? 511 : st); }
    rowoff[tid] = (b * 512 + st) * 512;
  }
  __syncthreads();
  const unsigned short* wih_d = wih + (size_t)dir * 1048576;
  f32x4 acc[4][4];
#pragma unroll
  for (int i = 0; i < 4; ++i)
#pragma unroll
    for (int j = 0; j < 4; ++j) acc[i][j] = f32x4{0.f, 0.f, 0.f, 0.f};
  const int w = tid >> 6, l = tid & 63;
  const int wm = w & 1, wn = w >> 1;
  for (int ks = 0; ks < 8; ++ks) {
    int k0 = ks * 64;
    __syncthreads();
#pragma unroll
    for (int r = 0; r < 8; ++r) {
      int u = tid + 256 * r;
      int plane = u >> 10;
      int rem = u & 1023;
      int row = rem >> 3, cph = rem & 7;
      int koff = k0 + (cph ^ (row & 7)) * 8;
      const unsigned short* src;
      if (plane == 0) src = xb + rowoff[row] + koff;
      else src = wih_d + (n0 + row) * 512 + koff;
      *(uint4*)(smem + u * 16) = *(const uint4*)src;
    }
    __syncthreads();
#pragma unroll
    for (int kf = 0; kf < 2; ++kf) {
      bf16x8 ah[4], bh[4];
#pragma unroll
      for (int x = 0; x < 4; ++x) {
        int arow = wm * 64 + x * 16 + (l & 15);
        int ac = (kf * 4 + (l >> 4)) ^ (arow & 7);
        ah[x] = *(const bf16x8*)(smem + arow * 128 + ac * 16);
        int brow = wn * 64 + x * 16 + (l & 15);
        int bc = (kf * 4 + (l >> 4)) ^ (brow & 7);
        bh[x] = *(const bf16x8*)(smem + 16384 + brow * 128 + bc * 16);
      }
#pragma unroll
      for (int mi = 0; mi < 4; ++mi)
#pragma unroll
        for (int ni = 0; ni < 4; ++ni)
          acc[mi][ni] = MFMA16(ah[mi], bh[ni], acc[mi][ni]);
    }
  }
  const float* bias = dir ? bias_b : bias_f;
  unsigned short* xpd = xp + (size_t)dir * (size_t)Tc * 131072;
#pragma unroll
  for (int mi = 0; mi < 4; ++mi)
#pragma unroll
    for (int ni = 0; ni < 4; ++ni)
#pragma unroll
      for (int i = 0; i < 4; ++i) {
        int m = m0 + wm * 64 + mi * 16 + (l >> 4) * 4 + i;
        int nn = n0 + wn * 64 + ni * 16 + (l & 15);
        int tlb = m >> 6, b = m & 63;
        int gate = nn >> 9, j = nn & 511;
        int wgl = j >> 4, un = j & 15;
        xpd[(size_t)tlb * 131072 + wgl * 4096 + gate * 1024 + b * 16 + un] =
            f2bf(acc[mi][ni][i] + bias[nn]);
      }
}

// ---------------- persistent recurrence (R10, unchanged) ----------------
__global__ __launch_bounds__(512) void lstm_persist(
    const unsigned short* __restrict__ whh,
    unsigned long long* hx,
    const unsigned short* __restrict__ xp,
    const int* __restrict__ length,
    float* __restrict__ Cst, float* __restrict__ Hst,
    unsigned short* __restrict__ outbf,
    unsigned* arrv, int t0, int Tc) {
  __shared__ char smem[86016];
  const int tid = threadIdx.x;
  const int wgid = blockIdx.x;
  const int dir = wgid >> 5;
  const int wgl = wgid & 31;
  const int j0 = wgl * 16;
  const unsigned short* whh_d = whh + (size_t)dir * 1048576;
  for (int u = tid; u < 4096; u += 512) {
    int uhs = u >> 11, rem = u & 2047;
    int ntile = rem >> 10, rem2 = rem & 1023;
    int ks = rem2 >> 6, ch = rem2 & 63;
    int kqs = ch >> 4, row = ch & 15;
    int rp = ntile * 16 + row;
    int gate = rp >> 3, un = rp & 7;
    int grow = gate * 512 + j0 + uhs * 8 + un;
    const unsigned short* src = whh_d + grow * 512 + (ks * 4 + kqs) * 8;
    *(uint4*)(smem + uhs * 32768 + ntile * 16384 + ks * 1024 + ch * 16) =
        *(const uint4*)src;
  }
  const int w = tid >> 6, l = tid & 63;
  const int mh = w >> 1, uh = w & 1;
  const char* wbB = smem + uh * 32768;
  const int bA = 16 * mh + (l & 15);
  const int kq = l >> 4;
  const int lb = l >> 2;
  const int gb = 16 * mh + lb;
  const int p = l & 3;
  const int ju = j0 + uh * 8 + 2 * p;
  const int lenb = length[gb];
  char* wsc = smem + 65536 + w * 2560;
  float* gexw = (float*)wsc;
  unsigned* hpack = (unsigned*)(wsc + 2176);
  const size_t sa = ((size_t)dir * 64 + gb) * 512 + ju;
  float ca, ha, cb, hb;
  if (t0 == 0) { ca = ha = cb = hb = 0.f; }
  else { ca = Cst[sa]; ha = Hst[sa]; cb = Cst[sa + 1]; hb = Hst[sa + 1]; }
  unsigned* myflag = arrv + dir * 32 + wgl;
  const unsigned* grp = arrv + dir * 32;
  __syncthreads();

  const unsigned* xpu = (const unsigned*)(xp + (size_t)dir * Tc * 131072);
  const int xoff = wgl * 2048 + gb * 8 + uh * 4 + p;
  unsigned X0 = xpu[xoff], X1 = xpu[xoff + 512],
           X2 = xpu[xoff + 1024], X3 = xpu[xoff + 1536];

  for (int tl = 0; tl < Tc; ++tl) {
    const int t = t0 + tl;
    const int cur = t & 1;
    const char* hAb = (const char*)hx +
                      ((size_t)(dir * 2 + cur) * 64 + bA) * 1024;
    u32x4 fA[16];
#pragma unroll
    for (int ks = 0; ks < 16; ++ks)
      fA[ks] = __builtin_nontemporal_load(
          (const u32x4*)(hAb + ks * 64 + kq * 16));
    __builtin_amdgcn_sched_barrier(0);
    int tn = (tl + 1 < Tc) ? tl + 1 : tl;
    const unsigned* xn = xpu + (size_t)tn * 65536 + xoff;
    unsigned N0 = xn[0], N1 = xn[512], N2 = xn[1024], N3 = xn[1536];
    __builtin_amdgcn_sched_barrier(0);
    f32x4 a0 = f32x4{0.f, 0.f, 0.f, 0.f}, a1 = f32x4{0.f, 0.f, 0.f, 0.f};
#pragma unroll
    for (int ks = 0; ks < 16; ++ks) {
      bf16x8 av = __builtin_bit_cast(bf16x8, fA[ks]);
      bf16x8 b0 = *(const bf16x8*)(wbB + ks * 1024 + l * 16);
      bf16x8 b1 = *(const bf16x8*)(wbB + 16384 + ks * 1024 + l * 16);
      a0 = MFMA16(av, b0, a0);
      a1 = MFMA16(av, b1, a1);
    }
#pragma unroll
    for (int i = 0; i < 4; ++i) {
      gexw[(kq * 4 + i) * 34 + (l & 15)] = a0[i];
      gexw[(kq * 4 + i) * 34 + 16 + (l & 15)] = a1[i];
    }
    asm volatile("s_waitcnt lgkmcnt(0)" ::: "memory");
    float2 G0 = *(const float2*)(gexw + lb * 34 + 2 * p);
    float2 G1 = *(const float2*)(gexw + lb * 34 + 8 + 2 * p);
    float2 G2 = *(const float2*)(gexw + lb * 34 + 16 + 2 * p);
    float2 G3 = *(const float2*)(gexw + lb * 34 + 24 + 2 * p);
    const bool m = (t < lenb);
    {
      float i_a = 1.f / (1.f + expf(-(G0.x + bf2f((unsigned short)(X0 & 0xffff)))));
      float f_a = 1.f / (1.f + expf(-(G1.x + bf2f((unsigned short)(X1 & 0xffff)))));
      float g_a = tanhf(G2.x + bf2f((unsigned short)(X2 & 0xffff)));
      float o_a = 1.f / (1.f + expf(-(G3.x + bf2f((unsigned short)(X3 & 0xffff)))));
      float cn = f_a * ca + i_a * g_a;
      float hn = o_a * tanhf(cn);
      ca = m ? cn : ca;
      ha = m ? hn : ha;
      float i_b = 1.f / (1.f + expf(-(G0.y + bf2f((unsigned short)(X0 >> 16)))));
      float f_b = 1.f / (1.f + expf(-(G1.y + bf2f((unsigned short)(X1 >> 16)))));
      float g_b = tanhf(G2.y + bf2f((unsigned short)(X2 >> 16)));
      float o_b = 1.f / (1.f + expf(-(G3.y + bf2f((unsigned short)(X3 >> 16)))));
      float cn2 = f_b * cb + i_b * g_b;
      float hn2 = o_b * tanhf(cn2);
      cb = m ? cn2 : cb;
      hb = m ? hn2 : hb;
    }
    unsigned hpk = (unsigned)f2bf(ha) | ((unsigned)f2bf(hb) << 16);
    hpack[lb * 4 + p] = hpk;
    if (dir == 0) {
      *(unsigned*)((char*)outbf + (((size_t)gb * 512 + t) * 512 + ju) * 2) =
          m ? hpk : 0u;
    } else if (m) {
      int tp = lenb - 1 - t;
      *(unsigned*)((char*)outbf + 33554432 +
                   (((size_t)gb * 512 + tp) * 512 + ju) * 2) = hpk;
    }
    asm volatile("s_waitcnt lgkmcnt(0)" ::: "memory");
    if (l < 32) {
      int b2 = l >> 1, hf = l & 1;
      unsigned long long pv = *(const unsigned long long*)(hpack + b2 * 4 + hf * 2);
      unsigned long long* dst =
          (unsigned long long*)((char*)hx +
                                ((size_t)(dir * 2 + (cur ^ 1)) * 64 + 16 * mh + b2) *
                                    1024 +
                                (size_t)(j0 + uh * 8) * 2 + hf * 8);
      __hip_atomic_store(dst, pv, __ATOMIC_RELAXED, __HIP_MEMORY_SCOPE_AGENT);
    }
    if (tl + 1 < Tc) {
      asm volatile("s_waitcnt vmcnt(0)" ::: "memory");
      __syncthreads();
      if (tid == 0)
        __hip_atomic_store(myflag, (unsigned)(tl + 1), __ATOMIC_RELAXED,
                           __HIP_MEMORY_SCOPE_AGENT);
      if (w == 0) {
        const unsigned e = (unsigned)(tl + 1);
        while (true) {
          unsigned v = __hip_atomic_load(grp + (l & 31), __ATOMIC_RELAXED,
                                         __HIP_MEMORY_SCOPE_AGENT);
          if (__all((int)(v >= e))) break;
          __builtin_amdgcn_s_sleep(1);
        }
        asm volatile("" ::: "memory");
      }
      __syncthreads();
    }
    X0 = N0; X1 = N1; X2 = N2; X3 = N3;
  }
  Cst[sa] = ca; Hst[sa] = ha;
  Cst[sa + 1] = cb; Hst[sa + 1] = hb;
}

// ---------------- DIAGNOSTIC copy: mode 0=full / 1=nosync / 2=nosync+noload
__global__ __launch_bounds__(512) void lstm_diag(
    const unsigned short* __restrict__ whh,
    unsigned long long* hx,
    const unsigned short* __restrict__ xp,
    const int* __restrict__ length,
    float* __restrict__ Cst, float* __restrict__ Hst,
    unsigned short* __restrict__ outbf,
    unsigned* arrv, int t0, int Tc, int mode) {
  __shared__ char smem[86016];
  const int tid = threadIdx.x;
  const int wgid = blockIdx.x;
  const int dir = wgid >> 5;
  const int wgl = wgid & 31;
  const int j0 = wgl * 16;
  const unsigned short* whh_d = whh + (size_t)dir * 1048576;
  for (int u = tid; u < 4096; u += 512) {
    int uhs = u >> 11, rem = u & 2047;
    int ntile = rem >> 10, rem2 = rem & 1023;
    int ks = rem2 >> 6, ch = rem2 & 63;
    int kqs = ch >> 4, row = ch & 15;
    int rp = ntile * 16 + row;
    int gate = rp >> 3, un = rp & 7;
    int grow = gate * 512 + j0 + uhs * 8 + un;
    const unsigned short* src = whh_d + grow * 512 + (ks * 4 + kqs) * 8;
    *(uint4*)(smem + uhs * 32768 + ntile * 16384 + ks * 1024 + ch * 16) =
        *(const uint4*)src;
  }
  const int w = tid >> 6, l = tid & 63;
  const int mh = w >> 1, uh = w & 1;
  const char* wbB = smem + uh * 32768;
  const int bA = 16 * mh + (l & 15);
  const int kq = l >> 4;
  const int lb = l >> 2;
  const int gb = 16 * mh + lb;
  const int p = l & 3;
  const int ju = j0 + uh * 8 + 2 * p;
  const int lenb = length[gb];
  char* wsc = smem + 65536 + w * 2560;
  float* gexw = (float*)wsc;
  unsigned* hpack = (unsigned*)(wsc + 2176);
  const size_t sa = ((size_t)dir * 64 + gb) * 512 + ju;
  float ca = 0.f, ha = 0.f, cb = 0.f, hb = 0.f;
  unsigned* myflag = arrv + dir * 32 + wgl;
  const unsigned* grp = arrv + dir * 32;
  __syncthreads();

  const unsigned* xpu = (const unsigned*)(xp + (size_t)dir * Tc * 131072);
  const int xoff = wgl * 2048 + gb * 8 + uh * 4 + p;
  unsigned X0 = xpu[xoff], X1 = xpu[xoff + 512],
           X2 = xpu[xoff + 1024], X3 = xpu[xoff + 1536];

  u32x4 fA[16];
  if (mode == 2) {  // preload once; reused every step
    const char* hAb = (const char*)hx + ((size_t)(dir * 2) * 64 + bA) * 1024;
#pragma unroll
    for (int ks = 0; ks < 16; ++ks)
      fA[ks] = __builtin_nontemporal_load(
          (const u32x4*)(hAb + ks * 64 + kq * 16));
  }

  for (int tl = 0; tl < Tc; ++tl) {
    const int t = t0 + tl;
    const int cur = t & 1;
    if (mode < 2) {
      const char* hAb = (const char*)hx +
                        ((size_t)(dir * 2 + cur) * 64 + bA) * 1024;
#pragma unroll
      for (int ks = 0; ks < 16; ++ks)
        fA[ks] = __builtin_nontemporal_load(
            (const u32x4*)(hAb + ks * 64 + kq * 16));
      __builtin_amdgcn_sched_barrier(0);
    }
    int tn = (tl + 1 < Tc) ? tl + 1 : tl;
    const unsigned* xn = xpu + (size_t)tn * 65536 + xoff;
    unsigned N0 = xn[0], N1 = xn[512], N2 = xn[1024], N3 = xn[1536];
    __builtin_amdgcn_sched_barrier(0);
    f32x4 a0 = f32x4{0.f, 0.f, 0.f, 0.f}, a1 = f32x4{0.f, 0.f, 0.f, 0.f};
#pragma unroll
    for (int ks = 0; ks < 16; ++ks) {
      bf16x8 av = __builtin_bit_cast(bf16x8, fA[ks]);
      bf16x8 b0 = *(const bf16x8*)(wbB + ks * 1024 + l * 16);
      bf16x8 b1 = *(const bf16x8*)(wbB + 16384 + ks * 1024 + l * 16);
      a0 = MFMA16(av, b0, a0);
      a1 = MFMA16(av, b1, a1);
    }
#pragma unroll
    for (int i = 0; i < 4; ++i) {
      gexw[(kq * 4 + i) * 34 + (l & 15)] = a0[i];
      gexw[(kq * 4 + i) * 34 + 16 + (l & 15)] = a1[i];
    }
    asm volatile("s_waitcnt lgkmcnt(0)" ::: "memory");
    float2 G0 = *(const float2*)(gexw + lb * 34 + 2 * p);
    float2 G1 = *(const float2*)(gexw + lb * 34 + 8 + 2 * p);
    float2 G2 = *(const float2*)(gexw + lb * 34 + 16 + 2 * p);
    float2 G3 = *(const float2*)(gexw + lb * 34 + 24 + 2 * p);
    const bool m = (t < lenb);
    {
      float i_a = 1.f / (1.f + expf(-(G0.x + bf2f((unsigned short)(X0 & 0xffff)))));
      float f_a = 1.f / (1.f + expf(-(G1.x + bf2f((unsigned short)(X1 & 0xffff)))));
      float g_a = tanhf(G2.x + bf2f((unsigned short)(X2 & 0xffff)));
      float o_a = 1.f / (1.f + expf(-(G3.x + bf2f((unsigned short)(X3 & 0xffff)))));
      float cn = f_a * ca + i_a * g_a;
      float hn = o_a * tanhf(cn);
      ca = m ? cn : ca;
      ha = m ? hn : ha;
      float i_b = 1.f / (1.f + expf(-(G0.y + bf2f((unsigned short)(X0 >> 16)))));
      float f_b = 1.f / (1.f + expf(-(G1.y + bf2f((unsigned short)(X1 >> 16)))));
      float g_b = tanhf(G2.y + bf2f((unsigned short)(X2 >> 16)));
      float o_b = 1.f / (1.f + expf(-(G3.y + bf2f((unsigned short)(X3 >> 16)))));
      float cn2 = f_b * cb + i_b * g_b;
      float hn2 = o_b * tanhf(cn2);
      cb = m ? cn2 : cb;
      hb = m ? hn2 : hb;
    }
    unsigned hpk = (unsigned)f2bf(ha) | ((unsigned)f2bf(hb) << 16);
    hpack[lb * 4 + p] = hpk;
    if (dir == 0) {
      *(unsigned*)((char*)outbf + (((size_t)gb * 512 + t) * 512 + ju) * 2) =
          m ? hpk : 0u;
    } else if (m) {
      int tp = lenb - 1 - t;
      *(unsigned*)((char*)outbf + 33554432 +
                   (((size_t)gb * 512 + tp) * 512 + ju) * 2) = hpk;
    }
    asm volatile("s_waitcnt lgkmcnt(0)" ::: "memory");
    if (l < 32) {
      int b2 = l >> 1, hf = l & 1;
      unsigned long long pv = *(const unsigned long long*)(hpack + b2 * 4 + hf * 2);
      unsigned long long* dst =
          (unsigned long long*)((char*)hx +
                                ((size_t)(dir * 2 + (cur ^ 1)) * 64 + 16 * mh + b2) *
                                    1024 +
                                (size_t)(j0 + uh * 8) * 2 + hf * 8);
      __hip_atomic_store(dst, pv, __ATOMIC_RELAXED, __HIP_MEMORY_SCOPE_AGENT);
    }
    if (mode == 0 && tl + 1 < Tc) {
      asm volatile("s_waitcnt vmcnt(0)" ::: "memory");
      __syncthreads();
      if (tid == 0)
        __hip_atomic_store(myflag, (unsigned)(tl + 1), __ATOMIC_RELAXED,
                           __HIP_MEMORY_SCOPE_AGENT);
      if (w == 0) {
        const unsigned e = (unsigned)(tl + 1);
        while (true) {
          unsigned v = __hip_atomic_load(grp + (l & 31), __ATOMIC_RELAXED,
                                         __HIP_MEMORY_SCOPE_AGENT);
          if (__all((int)(v >= e))) break;
          __builtin_amdgcn_s_sleep(1);
        }
        asm volatile("" ::: "memory");
      }
      __syncthreads();
    }
    X0 = N0; X1 = N1; X2 = N2; X3 = N3;
  }
  Cst[sa] = ca; Hst[sa] = ha;
  Cst[sa + 1] = cb; Hst[sa + 1] = hb;
}

// ---------------- emissions (unchanged) ----------------
__global__ __launch_bounds__(256) void emis_kernel(
    const unsigned short* __restrict__ outbf, const float* __restrict__ Wout,
    const float* __restrict__ bout, float* __restrict__ emis) {
  __shared__ float red[64][25][4];
  int tid = threadIdx.x;
  int p = tid >> 6, rr = tid & 63;
  int r = blockIdx.x * 64 + rr;
  int b = r >> 9, t = r & 511;
  int dir = p >> 1;
  int jq = (p & 1) * 256;
  const unsigned short* hp =
      outbf + (size_t)dir * 16777216 + ((size_t)b * 512 + t) * 512 + jq;
  float acc[24];
#pragma unroll
  for (int i = 0; i < 24; ++i) acc[i] = 0.f;
  for (int kc = 0; kc < 32; ++kc) {
    uint4 vh = *(const uint4*)(hp + kc * 8);
    unsigned uhv[4] = {vh.x, vh.y, vh.z, vh.w};
    float f[8];
#pragma unroll
    for (int z = 0; z < 4; ++z) {
      f[2 * z] = bf2f((unsigned short)(uhv[z] & 0xffff));
      f[2 * z + 1] = bf2f((unsigned short)(uhv[z] >> 16));
    }
    const float* wbase = Wout + dir * 512 + jq + kc * 8;
#pragma unroll
    for (int nn = 0; nn < 24; ++nn) {
      const float* wr = wbase + nn * 1024;
      float4 w0 = *(const float4*)(wr);
      float4 w1 = *(const float4*)(wr + 4);
      acc[nn] += f[0] * w0.x + f[1] * w0.y + f[2] * w0.z + f[3] * w0.w +
                 f[4] * w1.x + f[5] * w1.y + f[6] * w1.z + f[7] * w1.w;
    }
  }
#pragma unroll
  for (int nn = 0; nn < 24; ++nn) red[rr][nn][p] = acc[nn];
  __syncthreads();
#pragma unroll
  for (int oi = 0; oi < 6; ++oi) {
    int idx = tid + 256 * oi;
    int rr2 = idx / 24, n2 = idx % 24;
    float v = red[rr2][n2][0] + red[rr2][n2][1] + red[rr2][n2][2] +
              red[rr2][n2][3] + bout[n2];
    emis[((size_t)blockIdx.x * 64 + rr2) * 24 + n2] = v;
  }
}

// ---------------- Viterbi (unchanged) ----------------
__global__ __launch_bounds__(64) void viterbi_kernel(
    const float* __restrict__ emis, const int* __restrict__ length,
    const float* __restrict__ trans, float* __restrict__ out) {
  __shared__ float eb[12288];
  __shared__ float tr[576];
  __shared__ unsigned char bp[512 * 24];
  __shared__ unsigned char seq[512];
  int b = blockIdx.x, l = threadIdx.x;
  const float* ebg = emis + (size_t)b * 12288;
  for (int i = l * 4; i < 12288; i += 256)
    *(float4*)(eb + i) = *(const float4*)(ebg + i);
  for (int i = l; i < 576; i += 64) tr[i] = trans[i];
  __syncthreads();
  int lc = (l < 24) ? l : 0;
  float tcol[24];
#pragma unroll
  for (int p = 0; p < 24; ++p) tcol[p] = tr[p * 24 + lc];
  int len = length[b];
  float alpha = (l < 24) ? eb[lc] + tr[22 * 24 + lc] : -3e38f;
  for (int t = 1; t < 512; ++t) {
    float mx = -3e38f;
    int arg = 0;
#pragma unroll
    for (int p = 0; p < 24; ++p) {
      float v = __shfl(alpha, p) + tcol[p];
      if (v > mx) { mx = v; arg = p; }
    }
    if (l < 24) {
      bp[t * 24 + l] = (unsigned char)arg;
      if (t < len) alpha = mx + eb[t * 24 + l];
    }
  }
  float fin = (l < 24) ? alpha + tr[lc * 24 + 23] : -3e38f;
  float best = -3e38f;
  int cur = 0;
  for (int p = 0; p < 24; ++p) {
    float v = __shfl(fin, p);
    if (v > best) { best = v; cur = p; }
  }
  int last = len - 1;
  if (l == 0) {
    out[b] = best;
    int c = cur;
    for (int t = 511; t >= 0; --t) {
      seq[t] = (unsigned char)c;
      if (t >= 1 && t <= last) c = bp[t * 24 + c];
    }
  }
  __syncthreads();
  for (int i = l; i < 512; i += 64) out[64 + b * 512 + i] = (float)seq[i];
}

// ---------------- host ----------------
extern "C" void kernel_launch(void* const* d_in, const int* in_sizes, int n_in,
                              void* d_out, int out_size, void* d_ws, size_t ws_size,
                              hipStream_t stream) {
  const float* X = (const float*)d_in[0];
  const int* length = (const int*)d_in[2];
  const float* Wih_f = (const float*)d_in[3];
  const float* Whh_f = (const float*)d_in[4];
  const float* b_f = (const float*)d_in[5];
  const float* Wih_b = (const float*)d_in[6];
  const float* Whh_b = (const float*)d_in[7];
  const float* b_b = (const float*)d_in[8];
  const float* Wout = (const float*)d_in[9];
  const float* bout = (const float*)d_in[10];
  const float* trans = (const float*)d_in[11];

  char* ws = (char*)d_ws;
  unsigned short* whh_bf = (unsigned short*)(ws + O_WHHB);
  unsigned short* wih_bf = (unsigned short*)(ws + O_WIHB);
  unsigned short* xb = (unsigned short*)(ws + O_XB);
  unsigned short* outbf = (unsigned short*)(ws + O_OUT);
  unsigned long long* hx = (unsigned long long*)(ws + O_HX);
  float* Hbuf = (float*)(ws + O_HF);
  float* Cbuf = (float*)(ws + O_CF);
  float* emis = (float*)(ws + O_EMIS);
  unsigned* bar = (unsigned*)(ws + O_BAR);
  unsigned short* xp = (unsigned short*)(ws + O_XP);

  int Tc = 2;
  const int cands[9] = {512, 256, 128, 64, 32, 16, 8, 4, 2};
  for (int i = 0; i < 9; ++i) {
    if (O_XP + (size_t)cands[i] * 524288 <= ws_size) { Tc = cands[i]; break; }
  }
  int nch = T_ / Tc;

  hipMemsetAsync(ws + O_OUT, 0, SZ_OUT, stream);
  hipMemsetAsync(ws + O_HX, 0, SZ_HX, stream);

  cast_bf<<<1024, 256, 0, stream>>>(Whh_f, whh_bf, 1048576);
  cast_bf<<<1024, 256, 0, stream>>>(Whh_b, whh_bf + 1048576, 1048576);
  cast_bf<<<1024, 256, 0, stream>>>(Wih_f, wih_bf, 1048576);
  cast_bf<<<1024, 256, 0, stream>>>(Wih_b, wih_bf + 1048576, 1048576);
  cast_bf<<<4096, 256, 0, stream>>>(X, xb, 16777216);

  for (int ch = 0; ch < nch; ++ch) {
    int t0 = ch * Tc;
    xp_gemm<<<dim3(Tc * 64 / 128, 16, 2), 256, 0, stream>>>(
        xb, wih_bf, b_f, b_b, length, xp, t0, Tc);
    hipMemsetAsync(bar, 0, 2048, stream);
    lstm_persist<<<64, 512, 0, stream>>>(whh_bf, hx, xp, length, Cbuf, Hbuf,
                                         outbf, bar, 0 + t0, Tc);
  }
  emis_kernel<<<512, 256, 0, stream>>>(outbf, Wout, bout, emis);
  viterbi_kernel<<<64, 64, 0, stream>>>(emis, length, trans, (float*)d_out);

  // ---- diagnostics: scratch-only, run after d_out is final ----
  int Td = (Tc < 256) ? Tc : 256;
  hipMemsetAsync(bar, 0, 2048, stream);
  lstm_diag<<<64, 512, 0, stream>>>(whh_bf, hx, xp, length, Cbuf, Hbuf,
                                    outbf, bar, 0, Td, 0);
  lstm_diag<<<64, 512, 0, stream>>>(whh_bf, hx, xp, length, Cbuf, Hbuf,
                                    outbf, bar, 0, Td, 1);
  lstm_diag<<<64, 512, 0, stream>>>(whh_bf, hx, xp, length, Cbuf, Hbuf,
                                    outbf, bar, 0, Td, 2);
}

// Round 12
// 9913.343 us; speedup vs baseline: 1.0006x; 1.0006x over previous
//
#include <hip/hip_runtime.h>

// ============================================================================
// BiLSTM + CRF Viterbi.  Round 11: DIAGNOSTIC round.
//  Real pipeline = R10 exactly (unchanged, correct output).  After viterbi,
//  three scratch-only lstm_diag dispatches ablate the persist kernel:
//    mode 0: identical step loop (calibration)
//    mode 1: no sync (no drain/S2/flag/poll/S0) -> isolates sync+IF$ chain
//    mode 2: no sync + no fA loads               -> isolates h-read cost
//  They write only to already-consumed scratch (outbf/Cst/Hst/hx); d_out is
//  produced before they run -> correctness & determinism preserved.
// ============================================================================

#define B_ 64
#define T_ 512
#define NT_ 24

typedef __attribute__((ext_vector_type(8))) short bf16x8;
typedef __attribute__((ext_vector_type(4))) float f32x4;
typedef __attribute__((ext_vector_type(4))) unsigned int u32x4;

#define MFMA16(a, b, c) __builtin_amdgcn_mfma_f32_16x16x32_bf16(a, b, c, 0, 0, 0)

__device__ __forceinline__ unsigned short f2bf(float x) {
  unsigned u = __float_as_uint(x);
  u += 0x7FFFu + ((u >> 16) & 1u);
  return (unsigned short)(u >> 16);
}
__device__ __forceinline__ float bf2f(unsigned short h) {
  return __uint_as_float(((unsigned)h) << 16);
}

// ---------------- ws layout (bytes) ----------------
#define O_WHHB  ((size_t)0)
#define O_WIHB  ((size_t)4194304)
#define O_XB    ((size_t)8388608)
#define O_OUT   ((size_t)41943040)
#define SZ_OUT  ((size_t)67108864)
#define O_HX    ((size_t)109051904)
#define SZ_HX   ((size_t)262144)
#define O_HF    ((size_t)109314048)
#define O_CF    ((size_t)109576192)
#define O_EMIS  ((size_t)109838336)
#define O_BAR   ((size_t)112984064)
#define O_XP    ((size_t)112986112)

// ---------------- fp32 -> bf16 cast ----------------
__global__ void cast_bf(const float* __restrict__ src,
                        unsigned short* __restrict__ dst, int n) {
  int i = (blockIdx.x * blockDim.x + threadIdx.x) * 4;
  int stride = gridDim.x * blockDim.x * 4;
  for (; i < n; i += stride) {
    float4 v = *(const float4*)(src + i);
    ushort4 o;
    o.x = f2bf(v.x); o.y = f2bf(v.y); o.z = f2bf(v.z); o.w = f2bf(v.w);
    *(ushort4*)(dst + i) = o;
  }
}

// ---------------- xp GEMM (R10, unchanged) ----------------
__global__ __launch_bounds__(256) void xp_gemm(
    const unsigned short* __restrict__ xb,
    const unsigned short* __restrict__ wih,
    const float* __restrict__ bias_f, const float* __restrict__ bias_b,
    const int* __restrict__ length,
    unsigned short* __restrict__ xp, int t0, int Tc) {
  __shared__ char smem[32768];
  __shared__ int rowoff[128];
  const int tid = threadIdx.x;
  const int dir = blockIdx.z;
  const int m0 = blockIdx.x * 128;
  const int n0 = blockIdx.y * 128;
  if (tid < 128) {
    int m = m0 + tid;
    int tt = t0 + (m >> 6);
    int b = m & 63;
    int st = tt;
    if (dir) { st = length[b] - 1 - tt; st = st < 0 ? 0 : (st > 511 ? 511 : st); }
    rowoff[tid] = (b * 512 + st) * 512;
  }
  __syncthreads();
  const unsigned short* wih_d = wih + (size_t)dir * 1048576;
  f32x4 acc[4][4];
#pragma unroll
  for (int i = 0; i < 4; ++i)
#pragma unroll
    for (int j = 0; j < 4; ++j) acc[i][j] = f32x4{0.f, 0.f, 0.f, 0.f};
  const int w = tid >> 6, l = tid & 63;
  const int wm = w & 1, wn = w >> 1;
  for (int ks = 0; ks < 8; ++ks) {
    int k0 = ks * 64;
    __syncthreads();
#pragma unroll
    for (int r = 0; r < 8; ++r) {
      int u = tid + 256 * r;
      int plane = u >> 10;
      int rem = u & 1023;
      int row = rem >> 3, cph = rem & 7;
      int koff = k0 + (cph ^ (row & 7)) * 8;
      const unsigned short* src;
      if (plane == 0) src = xb + rowoff[row] + koff;
      else src = wih_d + (n0 + row) * 512 + koff;
      *(uint4*)(smem + u * 16) = *(const uint4*)src;
    }
    __syncthreads();
#pragma unroll
    for (int kf = 0; kf < 2; ++kf) {
      bf16x8 ah[4], bh[4];
#pragma unroll
      for (int x = 0; x < 4; ++x) {
        int arow = wm * 64 + x * 16 + (l & 15);
        int ac = (kf * 4 + (l >> 4)) ^ (arow & 7);
        ah[x] = *(const bf16x8*)(smem + arow * 128 + ac * 16);
        int brow = wn * 64 + x * 16 + (l & 15);
        int bc = (kf * 4 + (l >> 4)) ^ (brow & 7);
        bh[x] = *(const bf16x8*)(smem + 16384 + brow * 128 + bc * 16);
      }
#pragma unroll
      for (int mi = 0; mi < 4; ++mi)
#pragma unroll
        for (int ni = 0; ni < 4; ++ni)
          acc[mi][ni] = MFMA16(ah[mi], bh[ni], acc[mi][ni]);
    }
  }
  const float* bias = dir ? bias_b : bias_f;
  unsigned short* xpd = xp + (size_t)dir * (size_t)Tc * 131072;
#pragma unroll
  for (int mi = 0; mi < 4; ++mi)
#pragma unroll
    for (int ni = 0; ni < 4; ++ni)
#pragma unroll
      for (int i = 0; i < 4; ++i) {
        int m = m0 + wm * 64 + mi * 16 + (l >> 4) * 4 + i;
        int nn = n0 + wn * 64 + ni * 16 + (l & 15);
        int tlb = m >> 6, b = m & 63;
        int gate = nn >> 9, j = nn & 511;
        int wgl = j >> 4, un = j & 15;
        xpd[(size_t)tlb * 131072 + wgl * 4096 + gate * 1024 + b * 16 + un] =
            f2bf(acc[mi][ni][i] + bias[nn]);
      }
}

// ---------------- persistent recurrence (R10, unchanged) ----------------
__global__ __launch_bounds__(512) void lstm_persist(
    const unsigned short* __restrict__ whh,
    unsigned long long* hx,
    const unsigned short* __restrict__ xp,
    const int* __restrict__ length,
    float* __restrict__ Cst, float* __restrict__ Hst,
    unsigned short* __restrict__ outbf,
    unsigned* arrv, int t0, int Tc) {
  __shared__ char smem[86016];
  const int tid = threadIdx.x;
  const int wgid = blockIdx.x;
  const int dir = wgid >> 5;
  const int wgl = wgid & 31;
  const int j0 = wgl * 16;
  const unsigned short* whh_d = whh + (size_t)dir * 1048576;
  for (int u = tid; u < 4096; u += 512) {
    int uhs = u >> 11, rem = u & 2047;
    int ntile = rem >> 10, rem2 = rem & 1023;
    int ks = rem2 >> 6, ch = rem2 & 63;
    int kqs = ch >> 4, row = ch & 15;
    int rp = ntile * 16 + row;
    int gate = rp >> 3, un = rp & 7;
    int grow = gate * 512 + j0 + uhs * 8 + un;
    const unsigned short* src = whh_d + grow * 512 + (ks * 4 + kqs) * 8;
    *(uint4*)(smem + uhs * 32768 + ntile * 16384 + ks * 1024 + ch * 16) =
        *(const uint4*)src;
  }
  const int w = tid >> 6, l = tid & 63;
  const int mh = w >> 1, uh = w & 1;
  const char* wbB = smem + uh * 32768;
  const int bA = 16 * mh + (l & 15);
  const int kq = l >> 4;
  const int lb = l >> 2;
  const int gb = 16 * mh + lb;
  const int p = l & 3;
  const int ju = j0 + uh * 8 + 2 * p;
  const int lenb = length[gb];
  char* wsc = smem + 65536 + w * 2560;
  float* gexw = (float*)wsc;
  unsigned* hpack = (unsigned*)(wsc + 2176);
  const size_t sa = ((size_t)dir * 64 + gb) * 512 + ju;
  float ca, ha, cb, hb;
  if (t0 == 0) { ca = ha = cb = hb = 0.f; }
  else { ca = Cst[sa]; ha = Hst[sa]; cb = Cst[sa + 1]; hb = Hst[sa + 1]; }
  unsigned* myflag = arrv + dir * 32 + wgl;
  const unsigned* grp = arrv + dir * 32;
  __syncthreads();

  const unsigned* xpu = (const unsigned*)(xp + (size_t)dir * Tc * 131072);
  const int xoff = wgl * 2048 + gb * 8 + uh * 4 + p;
  unsigned X0 = xpu[xoff], X1 = xpu[xoff + 512],
           X2 = xpu[xoff + 1024], X3 = xpu[xoff + 1536];

  for (int tl = 0; tl < Tc; ++tl) {
    const int t = t0 + tl;
    const int cur = t & 1;
    const char* hAb = (const char*)hx +
                      ((size_t)(dir * 2 + cur) * 64 + bA) * 1024;
    u32x4 fA[16];
#pragma unroll
    for (int ks = 0; ks < 16; ++ks)
      fA[ks] = __builtin_nontemporal_load(
          (const u32x4*)(hAb + ks * 64 + kq * 16));
    __builtin_amdgcn_sched_barrier(0);
    int tn = (tl + 1 < Tc) ? tl + 1 : tl;
    const unsigned* xn = xpu + (size_t)tn * 65536 + xoff;
    unsigned N0 = xn[0], N1 = xn[512], N2 = xn[1024], N3 = xn[1536];
    __builtin_amdgcn_sched_barrier(0);
    f32x4 a0 = f32x4{0.f, 0.f, 0.f, 0.f}, a1 = f32x4{0.f, 0.f, 0.f, 0.f};
#pragma unroll
    for (int ks = 0; ks < 16; ++ks) {
      bf16x8 av = __builtin_bit_cast(bf16x8, fA[ks]);
      bf16x8 b0 = *(const bf16x8*)(wbB + ks * 1024 + l * 16);
      bf16x8 b1 = *(const bf16x8*)(wbB + 16384 + ks * 1024 + l * 16);
      a0 = MFMA16(av, b0, a0);
      a1 = MFMA16(av, b1, a1);
    }
#pragma unroll
    for (int i = 0; i < 4; ++i) {
      gexw[(kq * 4 + i) * 34 + (l & 15)] = a0[i];
      gexw[(kq * 4 + i) * 34 + 16 + (l & 15)] = a1[i];
    }
    asm volatile("s_waitcnt lgkmcnt(0)" ::: "memory");
    float2 G0 = *(const float2*)(gexw + lb * 34 + 2 * p);
    float2 G1 = *(const float2*)(gexw + lb * 34 + 8 + 2 * p);
    float2 G2 = *(const float2*)(gexw + lb * 34 + 16 + 2 * p);
    float2 G3 = *(const float2*)(gexw + lb * 34 + 24 + 2 * p);
    const bool m = (t < lenb);
    {
      float i_a = 1.f / (1.f + expf(-(G0.x + bf2f((unsigned short)(X0 & 0xffff)))));
      float f_a = 1.f / (1.f + expf(-(G1.x + bf2f((unsigned short)(X1 & 0xffff)))));
      float g_a = tanhf(G2.x + bf2f((unsigned short)(X2 & 0xffff)));
      float o_a = 1.f / (1.f + expf(-(G3.x + bf2f((unsigned short)(X3 & 0xffff)))));
      float cn = f_a * ca + i_a * g_a;
      float hn = o_a * tanhf(cn);
      ca = m ? cn : ca;
      ha = m ? hn : ha;
      float i_b = 1.f / (1.f + expf(-(G0.y + bf2f((unsigned short)(X0 >> 16)))));
      float f_b = 1.f / (1.f + expf(-(G1.y + bf2f((unsigned short)(X1 >> 16)))));
      float g_b = tanhf(G2.y + bf2f((unsigned short)(X2 >> 16)));
      float o_b = 1.f / (1.f + expf(-(G3.y + bf2f((unsigned short)(X3 >> 16)))));
      float cn2 = f_b * cb + i_b * g_b;
      float hn2 = o_b * tanhf(cn2);
      cb = m ? cn2 : cb;
      hb = m ? hn2 : hb;
    }
    unsigned hpk = (unsigned)f2bf(ha) | ((unsigned)f2bf(hb) << 16);
    hpack[lb * 4 + p] = hpk;
    if (dir == 0) {
      *(unsigned*)((char*)outbf + (((size_t)gb * 512 + t) * 512 + ju) * 2) =
          m ? hpk : 0u;
    } else if (m) {
      int tp = lenb - 1 - t;
      *(unsigned*)((char*)outbf + 33554432 +
                   (((size_t)gb * 512 + tp) * 512 + ju) * 2) = hpk;
    }
    asm volatile("s_waitcnt lgkmcnt(0)" ::: "memory");
    if (l < 32) {
      int b2 = l >> 1, hf = l & 1;
      unsigned long long pv = *(const unsigned long long*)(hpack + b2 * 4 + hf * 2);
      unsigned long long* dst =
          (unsigned long long*)((char*)hx +
                                ((size_t)(dir * 2 + (cur ^ 1)) * 64 + 16 * mh + b2) *
                                    1024 +
                                (size_t)(j0 + uh * 8) * 2 + hf * 8);
      __hip_atomic_store(dst, pv, __ATOMIC_RELAXED, __HIP_MEMORY_SCOPE_AGENT);
    }
    if (tl + 1 < Tc) {
      asm volatile("s_waitcnt vmcnt(0)" ::: "memory");
      __syncthreads();
      if (tid == 0)
        __hip_atomic_store(myflag, (unsigned)(tl + 1), __ATOMIC_RELAXED,
                           __HIP_MEMORY_SCOPE_AGENT);
      if (w == 0) {
        const unsigned e = (unsigned)(tl + 1);
        while (true) {
          unsigned v = __hip_atomic_load(grp + (l & 31), __ATOMIC_RELAXED,
                                         __HIP_MEMORY_SCOPE_AGENT);
          if (__all((int)(v >= e))) break;
          __builtin_amdgcn_s_sleep(1);
        }
        asm volatile("" ::: "memory");
      }
      __syncthreads();
    }
    X0 = N0; X1 = N1; X2 = N2; X3 = N3;
  }
  Cst[sa] = ca; Hst[sa] = ha;
  Cst[sa + 1] = cb; Hst[sa + 1] = hb;
}

// ---------------- DIAGNOSTIC copy: mode 0=full / 1=nosync / 2=nosync+noload
__global__ __launch_bounds__(512) void lstm_diag(
    const unsigned short* __restrict__ whh,
    unsigned long long* hx,
    const unsigned short* __restrict__ xp,
    const int* __restrict__ length,
    float* __restrict__ Cst, float* __restrict__ Hst,
    unsigned short* __restrict__ outbf,
    unsigned* arrv, int t0, int Tc, int mode) {
  __shared__ char smem[86016];
  const int tid = threadIdx.x;
  const int wgid = blockIdx.x;
  const int dir = wgid >> 5;
  const int wgl = wgid & 31;
  const int j0 = wgl * 16;
  const unsigned short* whh_d = whh + (size_t)dir * 1048576;
  for (int u = tid; u < 4096; u += 512) {
    int uhs = u >> 11, rem = u & 2047;
    int ntile = rem >> 10, rem2 = rem & 1023;
    int ks = rem2 >> 6, ch = rem2 & 63;
    int kqs = ch >> 4, row = ch & 15;
    int rp = ntile * 16 + row;
    int gate = rp >> 3, un = rp & 7;
    int grow = gate * 512 + j0 + uhs * 8 + un;
    const unsigned short* src = whh_d + grow * 512 + (ks * 4 + kqs) * 8;
    *(uint4*)(smem + uhs * 32768 + ntile * 16384 + ks * 1024 + ch * 16) =
        *(const uint4*)src;
  }
  const int w = tid >> 6, l = tid & 63;
  const int mh = w >> 1, uh = w & 1;
  const char* wbB = smem + uh * 32768;
  const int bA = 16 * mh + (l & 15);
  const int kq = l >> 4;
  const int lb = l >> 2;
  const int gb = 16 * mh + lb;
  const int p = l & 3;
  const int ju = j0 + uh * 8 + 2 * p;
  const int lenb = length[gb];
  char* wsc = smem + 65536 + w * 2560;
  float* gexw = (float*)wsc;
  unsigned* hpack = (unsigned*)(wsc + 2176);
  const size_t sa = ((size_t)dir * 64 + gb) * 512 + ju;
  float ca = 0.f, ha = 0.f, cb = 0.f, hb = 0.f;
  unsigned* myflag = arrv + dir * 32 + wgl;
  const unsigned* grp = arrv + dir * 32;
  __syncthreads();

  const unsigned* xpu = (const unsigned*)(xp + (size_t)dir * Tc * 131072);
  const int xoff = wgl * 2048 + gb * 8 + uh * 4 + p;
  unsigned X0 = xpu[xoff], X1 = xpu[xoff + 512],
           X2 = xpu[xoff + 1024], X3 = xpu[xoff + 1536];

  u32x4 fA[16];
  if (mode == 2) {  // preload once; reused every step
    const char* hAb = (const char*)hx + ((size_t)(dir * 2) * 64 + bA) * 1024;
#pragma unroll
    for (int ks = 0; ks < 16; ++ks)
      fA[ks] = __builtin_nontemporal_load(
          (const u32x4*)(hAb + ks * 64 + kq * 16));
  }

  for (int tl = 0; tl < Tc; ++tl) {
    const int t = t0 + tl;
    const int cur = t & 1;
    if (mode < 2) {
      const char* hAb = (const char*)hx +
                        ((size_t)(dir * 2 + cur) * 64 + bA) * 1024;
#pragma unroll
      for (int ks = 0; ks < 16; ++ks)
        fA[ks] = __builtin_nontemporal_load(
            (const u32x4*)(hAb + ks * 64 + kq * 16));
      __builtin_amdgcn_sched_barrier(0);
    }
    int tn = (tl + 1 < Tc) ? tl + 1 : tl;
    const unsigned* xn = xpu + (size_t)tn * 65536 + xoff;
    unsigned N0 = xn[0], N1 = xn[512], N2 = xn[1024], N3 = xn[1536];
    __builtin_amdgcn_sched_barrier(0);
    f32x4 a0 = f32x4{0.f, 0.f, 0.f, 0.f}, a1 = f32x4{0.f, 0.f, 0.f, 0.f};
#pragma unroll
    for (int ks = 0; ks < 16; ++ks) {
      bf16x8 av = __builtin_bit_cast(bf16x8, fA[ks]);
      bf16x8 b0 = *(const bf16x8*)(wbB + ks * 1024 + l * 16);
      bf16x8 b1 = *(const bf16x8*)(wbB + 16384 + ks * 1024 + l * 16);
      a0 = MFMA16(av, b0, a0);
      a1 = MFMA16(av, b1, a1);
    }
#pragma unroll
    for (int i = 0; i < 4; ++i) {
      gexw[(kq * 4 + i) * 34 + (l & 15)] = a0[i];
      gexw[(kq * 4 + i) * 34 + 16 + (l & 15)] = a1[i];
    }
    asm volatile("s_waitcnt lgkmcnt(0)" ::: "memory");
    float2 G0 = *(const float2*)(gexw + lb * 34 + 2 * p);
    float2 G1 = *(const float2*)(gexw + lb * 34 + 8 + 2 * p);
    float2 G2 = *(const float2*)(gexw + lb * 34 + 16 + 2 * p);
    float2 G3 = *(const float2*)(gexw + lb * 34 + 24 + 2 * p);
    const bool m = (t < lenb);
    {
      float i_a = 1.f / (1.f + expf(-(G0.x + bf2f((unsigned short)(X0 & 0xffff)))));
      float f_a = 1.f / (1.f + expf(-(G1.x + bf2f((unsigned short)(X1 & 0xffff)))));
      float g_a = tanhf(G2.x + bf2f((unsigned short)(X2 & 0xffff)));
      float o_a = 1.f / (1.f + expf(-(G3.x + bf2f((unsigned short)(X3 & 0xffff)))));
      float cn = f_a * ca + i_a * g_a;
      float hn = o_a * tanhf(cn);
      ca = m ? cn : ca;
      ha = m ? hn : ha;
      float i_b = 1.f / (1.f + expf(-(G0.y + bf2f((unsigned short)(X0 >> 16)))));
      float f_b = 1.f / (1.f + expf(-(G1.y + bf2f((unsigned short)(X1 >> 16)))));
      float g_b = tanhf(G2.y + bf2f((unsigned short)(X2 >> 16)));
      float o_b = 1.f / (1.f + expf(-(G3.y + bf2f((unsigned short)(X3 >> 16)))));
      float cn2 = f_b * cb + i_b * g_b;
      float hn2 = o_b * tanhf(cn2);
      cb = m ? cn2 : cb;
      hb = m ? hn2 : hb;
    }
    unsigned hpk = (unsigned)f2bf(ha) | ((unsigned)f2bf(hb) << 16);
    hpack[lb * 4 + p] = hpk;
    if (dir == 0) {
      *(unsigned*)((char*)outbf + (((size_t)gb * 512 + t) * 512 + ju) * 2) =
          m ? hpk : 0u;
    } else if (m) {
      int tp = lenb - 1 - t;
      *(unsigned*)((char*)outbf + 33554432 +
                   (((size_t)gb * 512 + tp) * 512 + ju) * 2) = hpk;
    }
    asm volatile("s_waitcnt lgkmcnt(0)" ::: "memory");
    if (l < 32) {
      int b2 = l >> 1, hf = l & 1;
      unsigned long long pv = *(const unsigned long long*)(hpack + b2 * 4 + hf * 2);
      unsigned long long* dst =
          (unsigned long long*)((char*)hx +
                                ((size_t)(dir * 2 + (cur ^ 1)) * 64 + 16 * mh + b2) *
                                    1024 +
                                (size_t)(j0 + uh * 8) * 2 + hf * 8);
      __hip_atomic_store(dst, pv, __ATOMIC_RELAXED, __HIP_MEMORY_SCOPE_AGENT);
    }
    if (mode == 0 && tl + 1 < Tc) {
      asm volatile("s_waitcnt vmcnt(0)" ::: "memory");
      __syncthreads();
      if (tid == 0)
        __hip_atomic_store(myflag, (unsigned)(tl + 1), __ATOMIC_RELAXED,
                           __HIP_MEMORY_SCOPE_AGENT);
      if (w == 0) {
        const unsigned e = (unsigned)(tl + 1);
        while (true) {
          unsigned v = __hip_atomic_load(grp + (l & 31), __ATOMIC_RELAXED,
                                         __HIP_MEMORY_SCOPE_AGENT);
          if (__all((int)(v >= e))) break;
          __builtin_amdgcn_s_sleep(1);
        }
        asm volatile("" ::: "memory");
      }
      __syncthreads();
    }
    X0 = N0; X1 = N1; X2 = N2; X3 = N3;
  }
  Cst[sa] = ca; Hst[sa] = ha;
  Cst[sa + 1] = cb; Hst[sa + 1] = hb;
}

// ---------------- emissions (unchanged) ----------------
__global__ __launch_bounds__(256) void emis_kernel(
    const unsigned short* __restrict__ outbf, const float* __restrict__ Wout,
    const float* __restrict__ bout, float* __restrict__ emis) {
  __shared__ float red[64][25][4];
  int tid = threadIdx.x;
  int p = tid >> 6, rr = tid & 63;
  int r = blockIdx.x * 64 + rr;
  int b = r >> 9, t = r & 511;
  int dir = p >> 1;
  int jq = (p & 1) * 256;
  const unsigned short* hp =
      outbf + (size_t)dir * 16777216 + ((size_t)b * 512 + t) * 512 + jq;
  float acc[24];
#pragma unroll
  for (int i = 0; i < 24; ++i) acc[i] = 0.f;
  for (int kc = 0; kc < 32; ++kc) {
    uint4 vh = *(const uint4*)(hp + kc * 8);
    unsigned uhv[4] = {vh.x, vh.y, vh.z, vh.w};
    float f[8];
#pragma unroll
    for (int z = 0; z < 4; ++z) {
      f[2 * z] = bf2f((unsigned short)(uhv[z] & 0xffff));
      f[2 * z + 1] = bf2f((unsigned short)(uhv[z] >> 16));
    }
    const float* wbase = Wout + dir * 512 + jq + kc * 8;
#pragma unroll
    for (int nn = 0; nn < 24; ++nn) {
      const float* wr = wbase + nn * 1024;
      float4 w0 = *(const float4*)(wr);
      float4 w1 = *(const float4*)(wr + 4);
      acc[nn] += f[0] * w0.x + f[1] * w0.y + f[2] * w0.z + f[3] * w0.w +
                 f[4] * w1.x + f[5] * w1.y + f[6] * w1.z + f[7] * w1.w;
    }
  }
#pragma unroll
  for (int nn = 0; nn < 24; ++nn) red[rr][nn][p] = acc[nn];
  __syncthreads();
#pragma unroll
  for (int oi = 0; oi < 6; ++oi) {
    int idx = tid + 256 * oi;
    int rr2 = idx / 24, n2 = idx % 24;
    float v = red[rr2][n2][0] + red[rr2][n2][1] + red[rr2][n2][2] +
              red[rr2][n2][3] + bout[n2];
    emis[((size_t)blockIdx.x * 64 + rr2) * 24 + n2] = v;
  }
}

// ---------------- Viterbi (unchanged) ----------------
__global__ __launch_bounds__(64) void viterbi_kernel(
    const float* __restrict__ emis, const int* __restrict__ length,
    const float* __restrict__ trans, float* __restrict__ out) {
  __shared__ float eb[12288];
  __shared__ float tr[576];
  __shared__ unsigned char bp[512 * 24];
  __shared__ unsigned char seq[512];
  int b = blockIdx.x, l = threadIdx.x;
  const float* ebg = emis + (size_t)b * 12288;
  for (int i = l * 4; i < 12288; i += 256)
    *(float4*)(eb + i) = *(const float4*)(ebg + i);
  for (int i = l; i < 576; i += 64) tr[i] = trans[i];
  __syncthreads();
  int lc = (l < 24) ? l : 0;
  float tcol[24];
#pragma unroll
  for (int p = 0; p < 24; ++p) tcol[p] = tr[p * 24 + lc];
  int len = length[b];
  float alpha = (l < 24) ? eb[lc] + tr[22 * 24 + lc] : -3e38f;
  for (int t = 1; t < 512; ++t) {
    float mx = -3e38f;
    int arg = 0;
#pragma unroll
    for (int p = 0; p < 24; ++p) {
      float v = __shfl(alpha, p) + tcol[p];
      if (v > mx) { mx = v; arg = p; }
    }
    if (l < 24) {
      bp[t * 24 + l] = (unsigned char)arg;
      if (t < len) alpha = mx + eb[t * 24 + l];
    }
  }
  float fin = (l < 24) ? alpha + tr[lc * 24 + 23] : -3e38f;
  float best = -3e38f;
  int cur = 0;
  for (int p = 0; p < 24; ++p) {
    float v = __shfl(fin, p);
    if (v > best) { best = v; cur = p; }
  }
  int last = len - 1;
  if (l == 0) {
    out[b] = best;
    int c = cur;
    for (int t = 511; t >= 0; --t) {
      seq[t] = (unsigned char)c;
      if (t >= 1 && t <= last) c = bp[t * 24 + c];
    }
  }
  __syncthreads();
  for (int i = l; i < 512; i += 64) out[64 + b * 512 + i] = (float)seq[i];
}

// ---------------- host ----------------
extern "C" void kernel_launch(void* const* d_in, const int* in_sizes, int n_in,
                              void* d_out, int out_size, void* d_ws, size_t ws_size,
                              hipStream_t stream) {
  const float* X = (const float*)d_in[0];
  const int* length = (const int*)d_in[2];
  const float* Wih_f = (const float*)d_in[3];
  const float* Whh_f = (const float*)d_in[4];
  const float* b_f = (const float*)d_in[5];
  const float* Wih_b = (const float*)d_in[6];
  const float* Whh_b = (const float*)d_in[7];
  const float* b_b = (const float*)d_in[8];
  const float* Wout = (const float*)d_in[9];
  const float* bout = (const float*)d_in[10];
  const float* trans = (const float*)d_in[11];

  char* ws = (char*)d_ws;
  unsigned short* whh_bf = (unsigned short*)(ws + O_WHHB);
  unsigned short* wih_bf = (unsigned short*)(ws + O_WIHB);
  unsigned short* xb = (unsigned short*)(ws + O_XB);
  unsigned short* outbf = (unsigned short*)(ws + O_OUT);
  unsigned long long* hx = (unsigned long long*)(ws + O_HX);
  float* Hbuf = (float*)(ws + O_HF);
  float* Cbuf = (float*)(ws + O_CF);
  float* emis = (float*)(ws + O_EMIS);
  unsigned* bar = (unsigned*)(ws + O_BAR);
  unsigned short* xp = (unsigned short*)(ws + O_XP);

  int Tc = 2;
  const int cands[9] = {512, 256, 128, 64, 32, 16, 8, 4, 2};
  for (int i = 0; i < 9; ++i) {
    if (O_XP + (size_t)cands[i] * 524288 <= ws_size) { Tc = cands[i]; break; }
  }
  int nch = T_ / Tc;

  hipMemsetAsync(ws + O_OUT, 0, SZ_OUT, stream);
  hipMemsetAsync(ws + O_HX, 0, SZ_HX, stream);

  cast_bf<<<1024, 256, 0, stream>>>(Whh_f, whh_bf, 1048576);
  cast_bf<<<1024, 256, 0, stream>>>(Whh_b, whh_bf + 1048576, 1048576);
  cast_bf<<<1024, 256, 0, stream>>>(Wih_f, wih_bf, 1048576);
  cast_bf<<<1024, 256, 0, stream>>>(Wih_b, wih_bf + 1048576, 1048576);
  cast_bf<<<4096, 256, 0, stream>>>(X, xb, 16777216);

  for (int ch = 0; ch < nch; ++ch) {
    int t0 = ch * Tc;
    xp_gemm<<<dim3(Tc * 64 / 128, 16, 2), 256, 0, stream>>>(
        xb, wih_bf, b_f, b_b, length, xp, t0, Tc);
    hipMemsetAsync(bar, 0, 2048, stream);
    lstm_persist<<<64, 512, 0, stream>>>(whh_bf, hx, xp, length, Cbuf, Hbuf,
                                         outbf, bar, 0 + t0, Tc);
  }
  emis_kernel<<<512, 256, 0, stream>>>(outbf, Wout, bout, emis);
  viterbi_kernel<<<64, 64, 0, stream>>>(emis, length, trans, (float*)d_out);

  // ---- diagnostics: scratch-only, run after d_out is final ----
  int Td = (Tc < 256) ? Tc : 256;
  hipMemsetAsync(bar, 0, 2048, stream);
  lstm_diag<<<64, 512, 0, stream>>>(whh_bf, hx, xp, length, Cbuf, Hbuf,
                                    outbf, bar, 0, Td, 0);
  lstm_diag<<<64, 512, 0, stream>>>(whh_bf, hx, xp, length, Cbuf, Hbuf,
                                    outbf, bar, 0, Td, 1);
  lstm_diag<<<64, 512, 0, stream>>>(whh_bf, hx, xp, length, Cbuf, Hbuf,
                                    outbf, bar, 0, Td, 2);
}

// Round 13
// 9815.620 us; speedup vs baseline: 1.0105x; 1.0100x over previous
//
#include <hip/hip_runtime.h>

// ============================================================================
// BiLSTM + CRF Viterbi.  Round 11: DIAGNOSTIC round.
//  Real pipeline = R10 exactly (unchanged, correct output).  After viterbi,
//  three scratch-only lstm_diag dispatches ablate the persist kernel:
//    mode 0: identical step loop (calibration)
//    mode 1: no sync (no drain/S2/flag/poll/S0) -> isolates sync+IF$ chain
//    mode 2: no sync + no fA loads               -> isolates h-read cost
//  They write only to already-consumed scratch (outbf/Cst/Hst/hx); d_out is
//  produced before they run -> correctness & determinism preserved.
// ============================================================================

#define B_ 64
#define T_ 512
#define NT_ 24

typedef __attribute__((ext_vector_type(8))) short bf16x8;
typedef __attribute__((ext_vector_type(4))) float f32x4;
typedef __attribute__((ext_vector_type(4))) unsigned int u32x4;

#define MFMA16(a, b, c) __builtin_amdgcn_mfma_f32_16x16x32_bf16(a, b, c, 0, 0, 0)

__device__ __forceinline__ unsigned short f2bf(float x) {
  unsigned u = __float_as_uint(x);
  u += 0x7FFFu + ((u >> 16) & 1u);
  return (unsigned short)(u >> 16);
}
__device__ __forceinline__ float bf2f(unsigned short h) {
  return __uint_as_float(((unsigned)h) << 16);
}

// ---------------- ws layout (bytes) ----------------
#define O_WHHB  ((size_t)0)
#define O_WIHB  ((size_t)4194304)
#define O_XB    ((size_t)8388608)
#define O_OUT   ((size_t)41943040)
#define SZ_OUT  ((size_t)67108864)
#define O_HX    ((size_t)109051904)
#define SZ_HX   ((size_t)262144)
#define O_HF    ((size_t)109314048)
#define O_CF    ((size_t)109576192)
#define O_EMIS  ((size_t)109838336)
#define O_BAR   ((size_t)112984064)
#define O_XP    ((size_t)112986112)

// ---------------- fp32 -> bf16 cast ----------------
__global__ void cast_bf(const float* __restrict__ src,
                        unsigned short* __restrict__ dst, int n) {
  int i = (blockIdx.x * blockDim.x + threadIdx.x) * 4;
  int stride = gridDim.x * blockDim.x * 4;
  for (; i < n; i += stride) {
    float4 v = *(const float4*)(src + i);
    ushort4 o;
    o.x = f2bf(v.x); o.y = f2bf(v.y); o.z = f2bf(v.z); o.w = f2bf(v.w);
    *(ushort4*)(dst + i) = o;
  }
}

// ---------------- xp GEMM (R10, unchanged) ----------------
__global__ __launch_bounds__(256) void xp_gemm(
    const unsigned short* __restrict__ xb,
    const unsigned short* __restrict__ wih,
    const float* __restrict__ bias_f, const float* __restrict__ bias_b,
    const int* __restrict__ length,
    unsigned short* __restrict__ xp, int t0, int Tc) {
  __shared__ char smem[32768];
  __shared__ int rowoff[128];
  const int tid = threadIdx.x;
  const int dir = blockIdx.z;
  const int m0 = blockIdx.x * 128;
  const int n0 = blockIdx.y * 128;
  if (tid < 128) {
    int m = m0 + tid;
    int tt = t0 + (m >> 6);
    int b = m & 63;
    int st = tt;
    if (dir) { st = length[b] - 1 - tt; st = st < 0 ? 0 : (st > 511 ? 511 : st); }
    rowoff[tid] = (b * 512 + st) * 512;
  }
  __syncthreads();
  const unsigned short* wih_d = wih + (size_t)dir * 1048576;
  f32x4 acc[4][4];
#pragma unroll
  for (int i = 0; i < 4; ++i)
#pragma unroll
    for (int j = 0; j < 4; ++j) acc[i][j] = f32x4{0.f, 0.f, 0.f, 0.f};
  const int w = tid >> 6, l = tid & 63;
  const int wm = w & 1, wn = w >> 1;
  for (int ks = 0; ks < 8; ++ks) {
    int k0 = ks * 64;
    __syncthreads();
#pragma unroll
    for (int r = 0; r < 8; ++r) {
      int u = tid + 256 * r;
      int plane = u >> 10;
      int rem = u & 1023;
      int row = rem >> 3, cph = rem & 7;
      int koff = k0 + (cph ^ (row & 7)) * 8;
      const unsigned short* src;
      if (plane == 0) src = xb + rowoff[row] + koff;
      else src = wih_d + (n0 + row) * 512 + koff;
      *(uint4*)(smem + u * 16) = *(const uint4*)src;
    }
    __syncthreads();
#pragma unroll
    for (int kf = 0; kf < 2; ++kf) {
      bf16x8 ah[4], bh[4];
#pragma unroll
      for (int x = 0; x < 4; ++x) {
        int arow = wm * 64 + x * 16 + (l & 15);
        int ac = (kf * 4 + (l >> 4)) ^ (arow & 7);
        ah[x] = *(const bf16x8*)(smem + arow * 128 + ac * 16);
        int brow = wn * 64 + x * 16 + (l & 15);
        int bc = (kf * 4 + (l >> 4)) ^ (brow & 7);
        bh[x] = *(const bf16x8*)(smem + 16384 + brow * 128 + bc * 16);
      }
#pragma unroll
      for (int mi = 0; mi < 4; ++mi)
#pragma unroll
        for (int ni = 0; ni < 4; ++ni)
          acc[mi][ni] = MFMA16(ah[mi], bh[ni], acc[mi][ni]);
    }
  }
  const float* bias = dir ? bias_b : bias_f;
  unsigned short* xpd = xp + (size_t)dir * (size_t)Tc * 131072;
#pragma unroll
  for (int mi = 0; mi < 4; ++mi)
#pragma unroll
    for (int ni = 0; ni < 4; ++ni)
#pragma unroll
      for (int i = 0; i < 4; ++i) {
        int m = m0 + wm * 64 + mi * 16 + (l >> 4) * 4 + i;
        int nn = n0 + wn * 64 + ni * 16 + (l & 15);
        int tlb = m >> 6, b = m & 63;
        int gate = nn >> 9, j = nn & 511;
        int wgl = j >> 4, un = j & 15;
        xpd[(size_t)tlb * 131072 + wgl * 4096 + gate * 1024 + b * 16 + un] =
            f2bf(acc[mi][ni][i] + bias[nn]);
      }
}

// ---------------- persistent recurrence (R10, unchanged) ----------------
__global__ __launch_bounds__(512) void lstm_persist(
    const unsigned short* __restrict__ whh,
    unsigned long long* hx,
    const unsigned short* __restrict__ xp,
    const int* __restrict__ length,
    float* __restrict__ Cst, float* __restrict__ Hst,
    unsigned short* __restrict__ outbf,
    unsigned* arrv, int t0, int Tc) {
  __shared__ char smem[86016];
  const int tid = threadIdx.x;
  const int wgid = blockIdx.x;
  const int dir = wgid >> 5;
  const int wgl = wgid & 31;
  const int j0 = wgl * 16;
  const unsigned short* whh_d = whh + (size_t)dir * 1048576;
  for (int u = tid; u < 4096; u += 512) {
    int uhs = u >> 11, rem = u & 2047;
    int ntile = rem >> 10, rem2 = rem & 1023;
    int ks = rem2 >> 6, ch = rem2 & 63;
    int kqs = ch >> 4, row = ch & 15;
    int rp = ntile * 16 + row;
    int gate = rp >> 3, un = rp & 7;
    int grow = gate * 512 + j0 + uhs * 8 + un;
    const unsigned short* src = whh_d + grow * 512 + (ks * 4 + kqs) * 8;
    *(uint4*)(smem + uhs * 32768 + ntile * 16384 + ks * 1024 + ch * 16) =
        *(const uint4*)src;
  }
  const int w = tid >> 6, l = tid & 63;
  const int mh = w >> 1, uh = w & 1;
  const char* wbB = smem + uh * 32768;
  const int bA = 16 * mh + (l & 15);
  const int kq = l >> 4;
  const int lb = l >> 2;
  const int gb = 16 * mh + lb;
  const int p = l & 3;
  const int ju = j0 + uh * 8 + 2 * p;
  const int lenb = length[gb];
  char* wsc = smem + 65536 + w * 2560;
  float* gexw = (float*)wsc;
  unsigned* hpack = (unsigned*)(wsc + 2176);
  const size_t sa = ((size_t)dir * 64 + gb) * 512 + ju;
  float ca, ha, cb, hb;
  if (t0 == 0) { ca = ha = cb = hb = 0.f; }
  else { ca = Cst[sa]; ha = Hst[sa]; cb = Cst[sa + 1]; hb = Hst[sa + 1]; }
  unsigned* myflag = arrv + dir * 32 + wgl;
  const unsigned* grp = arrv + dir * 32;
  __syncthreads();

  const unsigned* xpu = (const unsigned*)(xp + (size_t)dir * Tc * 131072);
  const int xoff = wgl * 2048 + gb * 8 + uh * 4 + p;
  unsigned X0 = xpu[xoff], X1 = xpu[xoff + 512],
           X2 = xpu[xoff + 1024], X3 = xpu[xoff + 1536];

  for (int tl = 0; tl < Tc; ++tl) {
    const int t = t0 + tl;
    const int cur = t & 1;
    const char* hAb = (const char*)hx +
                      ((size_t)(dir * 2 + cur) * 64 + bA) * 1024;
    u32x4 fA[16];
#pragma unroll
    for (int ks = 0; ks < 16; ++ks)
      fA[ks] = __builtin_nontemporal_load(
          (const u32x4*)(hAb + ks * 64 + kq * 16));
    __builtin_amdgcn_sched_barrier(0);
    int tn = (tl + 1 < Tc) ? tl + 1 : tl;
    const unsigned* xn = xpu + (size_t)tn * 65536 + xoff;
    unsigned N0 = xn[0], N1 = xn[512], N2 = xn[1024], N3 = xn[1536];
    __builtin_amdgcn_sched_barrier(0);
    f32x4 a0 = f32x4{0.f, 0.f, 0.f, 0.f}, a1 = f32x4{0.f, 0.f, 0.f, 0.f};
#pragma unroll
    for (int ks = 0; ks < 16; ++ks) {
      bf16x8 av = __builtin_bit_cast(bf16x8, fA[ks]);
      bf16x8 b0 = *(const bf16x8*)(wbB + ks * 1024 + l * 16);
      bf16x8 b1 = *(const bf16x8*)(wbB + 16384 + ks * 1024 + l * 16);
      a0 = MFMA16(av, b0, a0);
      a1 = MFMA16(av, b1, a1);
    }
#pragma unroll
    for (int i = 0; i < 4; ++i) {
      gexw[(kq * 4 + i) * 34 + (l & 15)] = a0[i];
      gexw[(kq * 4 + i) * 34 + 16 + (l & 15)] = a1[i];
    }
    asm volatile("s_waitcnt lgkmcnt(0)" ::: "memory");
    float2 G0 = *(const float2*)(gexw + lb * 34 + 2 * p);
    float2 G1 = *(const float2*)(gexw + lb * 34 + 8 + 2 * p);
    float2 G2 = *(const float2*)(gexw + lb * 34 + 16 + 2 * p);
    float2 G3 = *(const float2*)(gexw + lb * 34 + 24 + 2 * p);
    const bool m = (t < lenb);
    {
      float i_a = 1.f / (1.f + expf(-(G0.x + bf2f((unsigned short)(X0 & 0xffff)))));
      float f_a = 1.f / (1.f + expf(-(G1.x + bf2f((unsigned short)(X1 & 0xffff)))));
      float g_a = tanhf(G2.x + bf2f((unsigned short)(X2 & 0xffff)));
      float o_a = 1.f / (1.f + expf(-(G3.x + bf2f((unsigned short)(X3 & 0xffff)))));
      float cn = f_a * ca + i_a * g_a;
      float hn = o_a * tanhf(cn);
      ca = m ? cn : ca;
      ha = m ? hn : ha;
      float i_b = 1.f / (1.f + expf(-(G0.y + bf2f((unsigned short)(X0 >> 16)))));
      float f_b = 1.f / (1.f + expf(-(G1.y + bf2f((unsigned short)(X1 >> 16)))));
      float g_b = tanhf(G2.y + bf2f((unsigned short)(X2 >> 16)));
      float o_b = 1.f / (1.f + expf(-(G3.y + bf2f((unsigned short)(X3 >> 16)))));
      float cn2 = f_b * cb + i_b * g_b;
      float hn2 = o_b * tanhf(cn2);
      cb = m ? cn2 : cb;
      hb = m ? hn2 : hb;
    }
    unsigned hpk = (unsigned)f2bf(ha) | ((unsigned)f2bf(hb) << 16);
    hpack[lb * 4 + p] = hpk;
    if (dir == 0) {
      *(unsigned*)((char*)outbf + (((size_t)gb * 512 + t) * 512 + ju) * 2) =
          m ? hpk : 0u;
    } else if (m) {
      int tp = lenb - 1 - t;
      *(unsigned*)((char*)outbf + 33554432 +
                   (((size_t)gb * 512 + tp) * 512 + ju) * 2) = hpk;
    }
    asm volatile("s_waitcnt lgkmcnt(0)" ::: "memory");
    if (l < 32) {
      int b2 = l >> 1, hf = l & 1;
      unsigned long long pv = *(const unsigned long long*)(hpack + b2 * 4 + hf * 2);
      unsigned long long* dst =
          (unsigned long long*)((char*)hx +
                                ((size_t)(dir * 2 + (cur ^ 1)) * 64 + 16 * mh + b2) *
                                    1024 +
                                (size_t)(j0 + uh * 8) * 2 + hf * 8);
      __hip_atomic_store(dst, pv, __ATOMIC_RELAXED, __HIP_MEMORY_SCOPE_AGENT);
    }
    if (tl + 1 < Tc) {
      asm volatile("s_waitcnt vmcnt(0)" ::: "memory");
      __syncthreads();
      if (tid == 0)
        __hip_atomic_store(myflag, (unsigned)(tl + 1), __ATOMIC_RELAXED,
                           __HIP_MEMORY_SCOPE_AGENT);
      if (w == 0) {
        const unsigned e = (unsigned)(tl + 1);
        while (true) {
          unsigned v = __hip_atomic_load(grp + (l & 31), __ATOMIC_RELAXED,
                                         __HIP_MEMORY_SCOPE_AGENT);
          if (__all((int)(v >= e))) break;
          __builtin_amdgcn_s_sleep(1);
        }
        asm volatile("" ::: "memory");
      }
      __syncthreads();
    }
    X0 = N0; X1 = N1; X2 = N2; X3 = N3;
  }
  Cst[sa] = ca; Hst[sa] = ha;
  Cst[sa + 1] = cb; Hst[sa + 1] = hb;
}

// ---------------- DIAGNOSTIC copy: mode 0=full / 1=nosync / 2=nosync+noload
__global__ __launch_bounds__(512) void lstm_diag(
    const unsigned short* __restrict__ whh,
    unsigned long long* hx,
    const unsigned short* __restrict__ xp,
    const int* __restrict__ length,
    float* __restrict__ Cst, float* __restrict__ Hst,
    unsigned short* __restrict__ outbf,
    unsigned* arrv, int t0, int Tc, int mode) {
  __shared__ char smem[86016];
  const int tid = threadIdx.x;
  const int wgid = blockIdx.x;
  const int dir = wgid >> 5;
  const int wgl = wgid & 31;
  const int j0 = wgl * 16;
  const unsigned short* whh_d = whh + (size_t)dir * 1048576;
  for (int u = tid; u < 4096; u += 512) {
    int uhs = u >> 11, rem = u & 2047;
    int ntile = rem >> 10, rem2 = rem & 1023;
    int ks = rem2 >> 6, ch = rem2 & 63;
    int kqs = ch >> 4, row = ch & 15;
    int rp = ntile * 16 + row;
    int gate = rp >> 3, un = rp & 7;
    int grow = gate * 512 + j0 + uhs * 8 + un;
    const unsigned short* src = whh_d + grow * 512 + (ks * 4 + kqs) * 8;
    *(uint4*)(smem + uhs * 32768 + ntile * 16384 + ks * 1024 + ch * 16) =
        *(const uint4*)src;
  }
  const int w = tid >> 6, l = tid & 63;
  const int mh = w >> 1, uh = w & 1;
  const char* wbB = smem + uh * 32768;
  const int bA = 16 * mh + (l & 15);
  const int kq = l >> 4;
  const int lb = l >> 2;
  const int gb = 16 * mh + lb;
  const int p = l & 3;
  const int ju = j0 + uh * 8 + 2 * p;
  const int lenb = length[gb];
  char* wsc = smem + 65536 + w * 2560;
  float* gexw = (float*)wsc;
  unsigned* hpack = (unsigned*)(wsc + 2176);
  const size_t sa = ((size_t)dir * 64 + gb) * 512 + ju;
  float ca = 0.f, ha = 0.f, cb = 0.f, hb = 0.f;
  unsigned* myflag = arrv + dir * 32 + wgl;
  const unsigned* grp = arrv + dir * 32;
  __syncthreads();

  const unsigned* xpu = (const unsigned*)(xp + (size_t)dir * Tc * 131072);
  const int xoff = wgl * 2048 + gb * 8 + uh * 4 + p;
  unsigned X0 = xpu[xoff], X1 = xpu[xoff + 512],
           X2 = xpu[xoff + 1024], X3 = xpu[xoff + 1536];

  u32x4 fA[16];
  if (mode == 2) {  // preload once; reused every step
    const char* hAb = (const char*)hx + ((size_t)(dir * 2) * 64 + bA) * 1024;
#pragma unroll
    for (int ks = 0; ks < 16; ++ks)
      fA[ks] = __builtin_nontemporal_load(
          (const u32x4*)(hAb + ks * 64 + kq * 16));
  }

  for (int tl = 0; tl < Tc; ++tl) {
    const int t = t0 + tl;
    const int cur = t & 1;
    if (mode < 2) {
      const char* hAb = (const char*)hx +
                        ((size_t)(dir * 2 + cur) * 64 + bA) * 1024;
#pragma unroll
      for (int ks = 0; ks < 16; ++ks)
        fA[ks] = __builtin_nontemporal_load(
            (const u32x4*)(hAb + ks * 64 + kq * 16));
      __builtin_amdgcn_sched_barrier(0);
    }
    int tn = (tl + 1 < Tc) ? tl + 1 : tl;
    const unsigned* xn = xpu + (size_t)tn * 65536 + xoff;
    unsigned N0 = xn[0], N1 = xn[512], N2 = xn[1024], N3 = xn[1536];
    __builtin_amdgcn_sched_barrier(0);
    f32x4 a0 = f32x4{0.f, 0.f, 0.f, 0.f}, a1 = f32x4{0.f, 0.f, 0.f, 0.f};
#pragma unroll
    for (int ks = 0; ks < 16; ++ks) {
      bf16x8 av = __builtin_bit_cast(bf16x8, fA[ks]);
      bf16x8 b0 = *(const bf16x8*)(wbB + ks * 1024 + l * 16);
      bf16x8 b1 = *(const bf16x8*)(wbB + 16384 + ks * 1024 + l * 16);
      a0 = MFMA16(av, b0, a0);
      a1 = MFMA16(av, b1, a1);
    }
#pragma unroll
    for (int i = 0; i < 4; ++i) {
      gexw[(kq * 4 + i) * 34 + (l & 15)] = a0[i];
      gexw[(kq * 4 + i) * 34 + 16 + (l & 15)] = a1[i];
    }
    asm volatile("s_waitcnt lgkmcnt(0)" ::: "memory");
    float2 G0 = *(const float2*)(gexw + lb * 34 + 2 * p);
    float2 G1 = *(const float2*)(gexw + lb * 34 + 8 + 2 * p);
    float2 G2 = *(const float2*)(gexw + lb * 34 + 16 + 2 * p);
    float2 G3 = *(const float2*)(gexw + lb * 34 + 24 + 2 * p);
    const bool m = (t < lenb);
    {
      float i_a = 1.f / (1.f + expf(-(G0.x + bf2f((unsigned short)(X0 & 0xffff)))));
      float f_a = 1.f / (1.f + expf(-(G1.x + bf2f((unsigned short)(X1 & 0xffff)))));
      float g_a = tanhf(G2.x + bf2f((unsigned short)(X2 & 0xffff)));
      float o_a = 1.f / (1.f + expf(-(G3.x + bf2f((unsigned short)(X3 & 0xffff)))));
      float cn = f_a * ca + i_a * g_a;
      float hn = o_a * tanhf(cn);
      ca = m ? cn : ca;
      ha = m ? hn : ha;
      float i_b = 1.f / (1.f + expf(-(G0.y + bf2f((unsigned short)(X0 >> 16)))));
      float f_b = 1.f / (1.f + expf(-(G1.y + bf2f((unsigned short)(X1 >> 16)))));
      float g_b = tanhf(G2.y + bf2f((unsigned short)(X2 >> 16)));
      float o_b = 1.f / (1.f + expf(-(G3.y + bf2f((unsigned short)(X3 >> 16)))));
      float cn2 = f_b * cb + i_b * g_b;
      float hn2 = o_b * tanhf(cn2);
      cb = m ? cn2 : cb;
      hb = m ? hn2 : hb;
    }
    unsigned hpk = (unsigned)f2bf(ha) | ((unsigned)f2bf(hb) << 16);
    hpack[lb * 4 + p] = hpk;
    if (dir == 0) {
      *(unsigned*)((char*)outbf + (((size_t)gb * 512 + t) * 512 + ju) * 2) =
          m ? hpk : 0u;
    } else if (m) {
      int tp = lenb - 1 - t;
      *(unsigned*)((char*)outbf + 33554432 +
                   (((size_t)gb * 512 + tp) * 512 + ju) * 2) = hpk;
    }
    asm volatile("s_waitcnt lgkmcnt(0)" ::: "memory");
    if (l < 32) {
      int b2 = l >> 1, hf = l & 1;
      unsigned long long pv = *(const unsigned long long*)(hpack + b2 * 4 + hf * 2);
      unsigned long long* dst =
          (unsigned long long*)((char*)hx +
                                ((size_t)(dir * 2 + (cur ^ 1)) * 64 + 16 * mh + b2) *
                                    1024 +
                                (size_t)(j0 + uh * 8) * 2 + hf * 8);
      __hip_atomic_store(dst, pv, __ATOMIC_RELAXED, __HIP_MEMORY_SCOPE_AGENT);
    }
    if (mode == 0 && tl + 1 < Tc) {
      asm volatile("s_waitcnt vmcnt(0)" ::: "memory");
      __syncthreads();
      if (tid == 0)
        __hip_atomic_store(myflag, (unsigned)(tl + 1), __ATOMIC_RELAXED,
                           __HIP_MEMORY_SCOPE_AGENT);
      if (w == 0) {
        const unsigned e = (unsigned)(tl + 1);
        while (true) {
          unsigned v = __hip_atomic_load(grp + (l & 31), __ATOMIC_RELAXED,
                                         __HIP_MEMORY_SCOPE_AGENT);
          if (__all((int)(v >= e))) break;
          __builtin_amdgcn_s_sleep(1);
        }
        asm volatile("" ::: "memory");
      }
      __syncthreads();
    }
    X0 = N0; X1 = N1; X2 = N2; X3 = N3;
  }
  Cst[sa] = ca; Hst[sa] = ha;
  Cst[sa + 1] = cb; Hst[sa + 1] = hb;
}

// ---------------- emissions (unchanged) ----------------
__global__ __launch_bounds__(256) void emis_kernel(
    const unsigned short* __restrict__ outbf, const float* __restrict__ Wout,
    const float* __restrict__ bout, float* __restrict__ emis) {
  __shared__ float red[64][25][4];
  int tid = threadIdx.x;
  int p = tid >> 6, rr = tid & 63;
  int r = blockIdx.x * 64 + rr;
  int b = r >> 9, t = r & 511;
  int dir = p >> 1;
  int jq = (p & 1) * 256;
  const unsigned short* hp =
      outbf + (size_t)dir * 16777216 + ((size_t)b * 512 + t) * 512 + jq;
  float acc[24];
#pragma unroll
  for (int i = 0; i < 24; ++i) acc[i] = 0.f;
  for (int kc = 0; kc < 32; ++kc) {
    uint4 vh = *(const uint4*)(hp + kc * 8);
    unsigned uhv[4] = {vh.x, vh.y, vh.z, vh.w};
    float f[8];
#pragma unroll
    for (int z = 0; z < 4; ++z) {
      f[2 * z] = bf2f((unsigned short)(uhv[z] & 0xffff));
      f[2 * z + 1] = bf2f((unsigned short)(uhv[z] >> 16));
    }
    const float* wbase = Wout + dir * 512 + jq + kc * 8;
#pragma unroll
    for (int nn = 0; nn < 24; ++nn) {
      const float* wr = wbase + nn * 1024;
      float4 w0 = *(const float4*)(wr);
      float4 w1 = *(const float4*)(wr + 4);
      acc[nn] += f[0] * w0.x + f[1] * w0.y + f[2] * w0.z + f[3] * w0.w +
                 f[4] * w1.x + f[5] * w1.y + f[6] * w1.z + f[7] * w1.w;
    }
  }
#pragma unroll
  for (int nn = 0; nn < 24; ++nn) red[rr][nn][p] = acc[nn];
  __syncthreads();
#pragma unroll
  for (int oi = 0; oi < 6; ++oi) {
    int idx = tid + 256 * oi;
    int rr2 = idx / 24, n2 = idx % 24;
    float v = red[rr2][n2][0] + red[rr2][n2][1] + red[rr2][n2][2] +
              red[rr2][n2][3] + bout[n2];
    emis[((size_t)blockIdx.x * 64 + rr2) * 24 + n2] = v;
  }
}

// ---------------- Viterbi (unchanged) ----------------
__global__ __launch_bounds__(64) void viterbi_kernel(
    const float* __restrict__ emis, const int* __restrict__ length,
    const float* __restrict__ trans, float* __restrict__ out) {
  __shared__ float eb[12288];
  __shared__ float tr[576];
  __shared__ unsigned char bp[512 * 24];
  __shared__ unsigned char seq[512];
  int b = blockIdx.x, l = threadIdx.x;
  const float* ebg = emis + (size_t)b * 12288;
  for (int i = l * 4; i < 12288; i += 256)
    *(float4*)(eb + i) = *(const float4*)(ebg + i);
  for (int i = l; i < 576; i += 64) tr[i] = trans[i];
  __syncthreads();
  int lc = (l < 24) ? l : 0;
  float tcol[24];
#pragma unroll
  for (int p = 0; p < 24; ++p) tcol[p] = tr[p * 24 + lc];
  int len = length[b];
  float alpha = (l < 24) ? eb[lc] + tr[22 * 24 + lc] : -3e38f;
  for (int t = 1; t < 512; ++t) {
    float mx = -3e38f;
    int arg = 0;
#pragma unroll
    for (int p = 0; p < 24; ++p) {
      float v = __shfl(alpha, p) + tcol[p];
      if (v > mx) { mx = v; arg = p; }
    }
    if (l < 24) {
      bp[t * 24 + l] = (unsigned char)arg;
      if (t < len) alpha = mx + eb[t * 24 + l];
    }
  }
  float fin = (l < 24) ? alpha + tr[lc * 24 + 23] : -3e38f;
  float best = -3e38f;
  int cur = 0;
  for (int p = 0; p < 24; ++p) {
    float v = __shfl(fin, p);
    if (v > best) { best = v; cur = p; }
  }
  int last = len - 1;
  if (l == 0) {
    out[b] = best;
    int c = cur;
    for (int t = 511; t >= 0; --t) {
      seq[t] = (unsigned char)c;
      if (t >= 1 && t <= last) c = bp[t * 24 + c];
    }
  }
  __syncthreads();
  for (int i = l; i < 512; i += 64) out[64 + b * 512 + i] = (float)seq[i];
}

// ---------------- host ----------------
extern "C" void kernel_launch(void* const* d_in, const int* in_sizes, int n_in,
                              void* d_out, int out_size, void* d_ws, size_t ws_size,
                              hipStream_t stream) {
  const float* X = (const float*)d_in[0];
  const int* length = (const int*)d_in[2];
  const float* Wih_f = (const float*)d_in[3];
  const float* Whh_f = (const float*)d_in[4];
  const float* b_f = (const float*)d_in[5];
  const float* Wih_b = (const float*)d_in[6];
  const float* Whh_b = (const float*)d_in[7];
  const float* b_b = (const float*)d_in[8];
  const float* Wout = (const float*)d_in[9];
  const float* bout = (const float*)d_in[10];
  const float* trans = (const float*)d_in[11];

  char* ws = (char*)d_ws;
  unsigned short* whh_bf = (unsigned short*)(ws + O_WHHB);
  unsigned short* wih_bf = (unsigned short*)(ws + O_WIHB);
  unsigned short* xb = (unsigned short*)(ws + O_XB);
  unsigned short* outbf = (unsigned short*)(ws + O_OUT);
  unsigned long long* hx = (unsigned long long*)(ws + O_HX);
  float* Hbuf = (float*)(ws + O_HF);
  float* Cbuf = (float*)(ws + O_CF);
  float* emis = (float*)(ws + O_EMIS);
  unsigned* bar = (unsigned*)(ws + O_BAR);
  unsigned short* xp = (unsigned short*)(ws + O_XP);

  int Tc = 2;
  const int cands[9] = {512, 256, 128, 64, 32, 16, 8, 4, 2};
  for (int i = 0; i < 9; ++i) {
    if (O_XP + (size_t)cands[i] * 524288 <= ws_size) { Tc = cands[i]; break; }
  }
  int nch = T_ / Tc;

  hipMemsetAsync(ws + O_OUT, 0, SZ_OUT, stream);
  hipMemsetAsync(ws + O_HX, 0, SZ_HX, stream);

  cast_bf<<<1024, 256, 0, stream>>>(Whh_f, whh_bf, 1048576);
  cast_bf<<<1024, 256, 0, stream>>>(Whh_b, whh_bf + 1048576, 1048576);
  cast_bf<<<1024, 256, 0, stream>>>(Wih_f, wih_bf, 1048576);
  cast_bf<<<1024, 256, 0, stream>>>(Wih_b, wih_bf + 1048576, 1048576);
  cast_bf<<<4096, 256, 0, stream>>>(X, xb, 16777216);

  for (int ch = 0; ch < nch; ++ch) {
    int t0 = ch * Tc;
    xp_gemm<<<dim3(Tc * 64 / 128, 16, 2), 256, 0, stream>>>(
        xb, wih_bf, b_f, b_b, length, xp, t0, Tc);
    hipMemsetAsync(bar, 0, 2048, stream);
    lstm_persist<<<64, 512, 0, stream>>>(whh_bf, hx, xp, length, Cbuf, Hbuf,
                                         outbf, bar, 0 + t0, Tc);
  }
  emis_kernel<<<512, 256, 0, stream>>>(outbf, Wout, bout, emis);
  viterbi_kernel<<<64, 64, 0, stream>>>(emis, length, trans, (float*)d_out);

  // ---- diagnostics: scratch-only, run after d_out is final ----
  int Td = (Tc < 256) ? Tc : 256;
  hipMemsetAsync(bar, 0, 2048, stream);
  lstm_diag<<<64, 512, 0, stream>>>(whh_bf, hx, xp, length, Cbuf, Hbuf,
                                    outbf, bar, 0, Td, 0);
  lstm_diag<<<64, 512, 0, stream>>>(whh_bf, hx, xp, length, Cbuf, Hbuf,
                                    outbf, bar, 0, Td, 1);
  lstm_diag<<<64, 512, 0, stream>>>(whh_bf, hx, xp, length, Cbuf, Hbuf,
                                    outbf, bar, 0, Td, 2);
}

// Round 14
// 4031.770 us; speedup vs baseline: 2.4602x; 2.4346x over previous
//
#include <hip/hip_runtime.h>

// ============================================================================
// BiLSTM + CRF Viterbi.  Round 12: cached h-reads + per-step acquire-inv.
//  R11 ablation verdict: sync ~free; base compute ~1.6us/step; the nt h-load
//  path alone ~7us/step (uncacheable 64B transactions, 64x fan-out, no MSHR
//  merge).  Fix: normal cached loads for fA; poll wave issues ONE acquire
//  agent load after poll success (emits L1+L2 invalidate; 1 wg/CU so it
//  covers all 8 waves) before the S0 release barrier.  Acquire-ONLY (R3's
//  cost was the release wbl2).  Everything else identical to R10.
// ============================================================================

#define B_ 64
#define T_ 512
#define NT_ 24

typedef __attribute__((ext_vector_type(8))) short bf16x8;
typedef __attribute__((ext_vector_type(4))) float f32x4;
typedef __attribute__((ext_vector_type(4))) unsigned int u32x4;

#define MFMA16(a, b, c) __builtin_amdgcn_mfma_f32_16x16x32_bf16(a, b, c, 0, 0, 0)

__device__ __forceinline__ unsigned short f2bf(float x) {
  unsigned u = __float_as_uint(x);
  u += 0x7FFFu + ((u >> 16) & 1u);
  return (unsigned short)(u >> 16);
}
__device__ __forceinline__ float bf2f(unsigned short h) {
  return __uint_as_float(((unsigned)h) << 16);
}

// ---------------- ws layout (bytes) ----------------
#define O_WHHB  ((size_t)0)
#define O_WIHB  ((size_t)4194304)
#define O_XB    ((size_t)8388608)
#define O_OUT   ((size_t)41943040)
#define SZ_OUT  ((size_t)67108864)
#define O_HX    ((size_t)109051904)
#define SZ_HX   ((size_t)262144)
#define O_HF    ((size_t)109314048)
#define O_CF    ((size_t)109576192)
#define O_EMIS  ((size_t)109838336)
#define O_BAR   ((size_t)112984064)
#define O_XP    ((size_t)112986112)

// ---------------- fp32 -> bf16 cast ----------------
__global__ void cast_bf(const float* __restrict__ src,
                        unsigned short* __restrict__ dst, int n) {
  int i = (blockIdx.x * blockDim.x + threadIdx.x) * 4;
  int stride = gridDim.x * blockDim.x * 4;
  for (; i < n; i += stride) {
    float4 v = *(const float4*)(src + i);
    ushort4 o;
    o.x = f2bf(v.x); o.y = f2bf(v.y); o.z = f2bf(v.z); o.w = f2bf(v.w);
    *(ushort4*)(dst + i) = o;
  }
}

// ---------------- xp GEMM (R10, unchanged) ----------------
__global__ __launch_bounds__(256) void xp_gemm(
    const unsigned short* __restrict__ xb,
    const unsigned short* __restrict__ wih,
    const float* __restrict__ bias_f, const float* __restrict__ bias_b,
    const int* __restrict__ length,
    unsigned short* __restrict__ xp, int t0, int Tc) {
  __shared__ char smem[32768];
  __shared__ int rowoff[128];
  const int tid = threadIdx.x;
  const int dir = blockIdx.z;
  const int m0 = blockIdx.x * 128;
  const int n0 = blockIdx.y * 128;
  if (tid < 128) {
    int m = m0 + tid;
    int tt = t0 + (m >> 6);
    int b = m & 63;
    int st = tt;
    if (dir) { st = length[b] - 1 - tt; st = st < 0 ? 0 : (st > 511 ? 511 : st); }
    rowoff[tid] = (b * 512 + st) * 512;
  }
  __syncthreads();
  const unsigned short* wih_d = wih + (size_t)dir * 1048576;
  f32x4 acc[4][4];
#pragma unroll
  for (int i = 0; i < 4; ++i)
#pragma unroll
    for (int j = 0; j < 4; ++j) acc[i][j] = f32x4{0.f, 0.f, 0.f, 0.f};
  const int w = tid >> 6, l = tid & 63;
  const int wm = w & 1, wn = w >> 1;
  for (int ks = 0; ks < 8; ++ks) {
    int k0 = ks * 64;
    __syncthreads();
#pragma unroll
    for (int r = 0; r < 8; ++r) {
      int u = tid + 256 * r;
      int plane = u >> 10;
      int rem = u & 1023;
      int row = rem >> 3, cph = rem & 7;
      int koff = k0 + (cph ^ (row & 7)) * 8;
      const unsigned short* src;
      if (plane == 0) src = xb + rowoff[row] + koff;
      else src = wih_d + (n0 + row) * 512 + koff;
      *(uint4*)(smem + u * 16) = *(const uint4*)src;
    }
    __syncthreads();
#pragma unroll
    for (int kf = 0; kf < 2; ++kf) {
      bf16x8 ah[4], bh[4];
#pragma unroll
      for (int x = 0; x < 4; ++x) {
        int arow = wm * 64 + x * 16 + (l & 15);
        int ac = (kf * 4 + (l >> 4)) ^ (arow & 7);
        ah[x] = *(const bf16x8*)(smem + arow * 128 + ac * 16);
        int brow = wn * 64 + x * 16 + (l & 15);
        int bc = (kf * 4 + (l >> 4)) ^ (brow & 7);
        bh[x] = *(const bf16x8*)(smem + 16384 + brow * 128 + bc * 16);
      }
#pragma unroll
      for (int mi = 0; mi < 4; ++mi)
#pragma unroll
        for (int ni = 0; ni < 4; ++ni)
          acc[mi][ni] = MFMA16(ah[mi], bh[ni], acc[mi][ni]);
    }
  }
  const float* bias = dir ? bias_b : bias_f;
  unsigned short* xpd = xp + (size_t)dir * (size_t)Tc * 131072;
#pragma unroll
  for (int mi = 0; mi < 4; ++mi)
#pragma unroll
    for (int ni = 0; ni < 4; ++ni)
#pragma unroll
      for (int i = 0; i < 4; ++i) {
        int m = m0 + wm * 64 + mi * 16 + (l >> 4) * 4 + i;
        int nn = n0 + wn * 64 + ni * 16 + (l & 15);
        int tlb = m >> 6, b = m & 63;
        int gate = nn >> 9, j = nn & 511;
        int wgl = j >> 4, un = j & 15;
        xpd[(size_t)tlb * 131072 + wgl * 4096 + gate * 1024 + b * 16 + un] =
            f2bf(acc[mi][ni][i] + bias[nn]);
      }
}

// ---------------- persistent recurrence v8: cached fA + acquire-inv -------
__global__ __launch_bounds__(512) void lstm_persist(
    const unsigned short* __restrict__ whh,
    unsigned long long* hx,
    const unsigned short* __restrict__ xp,
    const int* __restrict__ length,
    float* __restrict__ Cst, float* __restrict__ Hst,
    unsigned short* __restrict__ outbf,
    unsigned* arrv, int t0, int Tc) {
  __shared__ char smem[86016];
  const int tid = threadIdx.x;
  const int wgid = blockIdx.x;
  const int dir = wgid >> 5;
  const int wgl = wgid & 31;
  const int j0 = wgl * 16;
  const unsigned short* whh_d = whh + (size_t)dir * 1048576;
  for (int u = tid; u < 4096; u += 512) {
    int uhs = u >> 11, rem = u & 2047;
    int ntile = rem >> 10, rem2 = rem & 1023;
    int ks = rem2 >> 6, ch = rem2 & 63;
    int kqs = ch >> 4, row = ch & 15;
    int rp = ntile * 16 + row;
    int gate = rp >> 3, un = rp & 7;
    int grow = gate * 512 + j0 + uhs * 8 + un;
    const unsigned short* src = whh_d + grow * 512 + (ks * 4 + kqs) * 8;
    *(uint4*)(smem + uhs * 32768 + ntile * 16384 + ks * 1024 + ch * 16) =
        *(const uint4*)src;
  }
  const int w = tid >> 6, l = tid & 63;
  const int mh = w >> 1, uh = w & 1;
  const char* wbB = smem + uh * 32768;
  const int bA = 16 * mh + (l & 15);
  const int kq = l >> 4;
  const int lb = l >> 2;
  const int gb = 16 * mh + lb;
  const int p = l & 3;
  const int ju = j0 + uh * 8 + 2 * p;
  const int lenb = length[gb];
  char* wsc = smem + 65536 + w * 2560;
  float* gexw = (float*)wsc;
  unsigned* hpack = (unsigned*)(wsc + 2176);
  const size_t sa = ((size_t)dir * 64 + gb) * 512 + ju;
  float ca, ha, cb, hb;
  if (t0 == 0) { ca = ha = cb = hb = 0.f; }
  else { ca = Cst[sa]; ha = Hst[sa]; cb = Cst[sa + 1]; hb = Hst[sa + 1]; }
  unsigned* myflag = arrv + dir * 32 + wgl;
  const unsigned* grp = arrv + dir * 32;
  __syncthreads();

  const unsigned* xpu = (const unsigned*)(xp + (size_t)dir * Tc * 131072);
  const int xoff = wgl * 2048 + gb * 8 + uh * 4 + p;
  unsigned X0 = xpu[xoff], X1 = xpu[xoff + 512],
           X2 = xpu[xoff + 1024], X3 = xpu[xoff + 1536];

  for (int tl = 0; tl < Tc; ++tl) {
    const int t = t0 + tl;
    const int cur = t & 1;
    // ---- fA loads: NORMAL cached loads (L1/L2 valid per acquire-inv) ----
    const char* hAb = (const char*)hx +
                      ((size_t)(dir * 2 + cur) * 64 + bA) * 1024;
    u32x4 fA[16];
#pragma unroll
    for (int ks = 0; ks < 16; ++ks)
      fA[ks] = *(const u32x4*)(hAb + ks * 64 + kq * 16);
    __builtin_amdgcn_sched_barrier(0);
    int tn = (tl + 1 < Tc) ? tl + 1 : tl;
    const unsigned* xn = xpu + (size_t)tn * 65536 + xoff;
    unsigned N0 = xn[0], N1 = xn[512], N2 = xn[1024], N3 = xn[1536];
    __builtin_amdgcn_sched_barrier(0);
    f32x4 a0 = f32x4{0.f, 0.f, 0.f, 0.f}, a1 = f32x4{0.f, 0.f, 0.f, 0.f};
#pragma unroll
    for (int ks = 0; ks < 16; ++ks) {
      bf16x8 av = __builtin_bit_cast(bf16x8, fA[ks]);
      bf16x8 b0 = *(const bf16x8*)(wbB + ks * 1024 + l * 16);
      bf16x8 b1 = *(const bf16x8*)(wbB + 16384 + ks * 1024 + l * 16);
      a0 = MFMA16(av, b0, a0);
      a1 = MFMA16(av, b1, a1);
    }
#pragma unroll
    for (int i = 0; i < 4; ++i) {
      gexw[(kq * 4 + i) * 34 + (l & 15)] = a0[i];
      gexw[(kq * 4 + i) * 34 + 16 + (l & 15)] = a1[i];
    }
    asm volatile("s_waitcnt lgkmcnt(0)" ::: "memory");
    float2 G0 = *(const float2*)(gexw + lb * 34 + 2 * p);
    float2 G1 = *(const float2*)(gexw + lb * 34 + 8 + 2 * p);
    float2 G2 = *(const float2*)(gexw + lb * 34 + 16 + 2 * p);
    float2 G3 = *(const float2*)(gexw + lb * 34 + 24 + 2 * p);
    const bool m = (t < lenb);
    {
      float i_a = 1.f / (1.f + expf(-(G0.x + bf2f((unsigned short)(X0 & 0xffff)))));
      float f_a = 1.f / (1.f + expf(-(G1.x + bf2f((unsigned short)(X1 & 0xffff)))));
      float g_a = tanhf(G2.x + bf2f((unsigned short)(X2 & 0xffff)));
      float o_a = 1.f / (1.f + expf(-(G3.x + bf2f((unsigned short)(X3 & 0xffff)))));
      float cn = f_a * ca + i_a * g_a;
      float hn = o_a * tanhf(cn);
      ca = m ? cn : ca;
      ha = m ? hn : ha;
      float i_b = 1.f / (1.f + expf(-(G0.y + bf2f((unsigned short)(X0 >> 16)))));
      float f_b = 1.f / (1.f + expf(-(G1.y + bf2f((unsigned short)(X1 >> 16)))));
      float g_b = tanhf(G2.y + bf2f((unsigned short)(X2 >> 16)));
      float o_b = 1.f / (1.f + expf(-(G3.y + bf2f((unsigned short)(X3 >> 16)))));
      float cn2 = f_b * cb + i_b * g_b;
      float hn2 = o_b * tanhf(cn2);
      cb = m ? cn2 : cb;
      hb = m ? hn2 : hb;
    }
    unsigned hpk = (unsigned)f2bf(ha) | ((unsigned)f2bf(hb) << 16);
    hpack[lb * 4 + p] = hpk;
    if (dir == 0) {
      *(unsigned*)((char*)outbf + (((size_t)gb * 512 + t) * 512 + ju) * 2) =
          m ? hpk : 0u;
    } else if (m) {
      int tp = lenb - 1 - t;
      *(unsigned*)((char*)outbf + 33554432 +
                   (((size_t)gb * 512 + tp) * 512 + ju) * 2) = hpk;
    }
    asm volatile("s_waitcnt lgkmcnt(0)" ::: "memory");
    if (l < 32) {
      int b2 = l >> 1, hf = l & 1;
      unsigned long long pv = *(const unsigned long long*)(hpack + b2 * 4 + hf * 2);
      unsigned long long* dst =
          (unsigned long long*)((char*)hx +
                                ((size_t)(dir * 2 + (cur ^ 1)) * 64 + 16 * mh + b2) *
                                    1024 +
                                (size_t)(j0 + uh * 8) * 2 + hf * 8);
      __hip_atomic_store(dst, pv, __ATOMIC_RELAXED, __HIP_MEMORY_SCOPE_AGENT);
    }
    if (tl + 1 < Tc) {
      asm volatile("s_waitcnt vmcnt(0)" ::: "memory");
      __syncthreads();  // S2: all waves' h-stores acked at coherence point
      if (tid == 0)
        __hip_atomic_store(myflag, (unsigned)(tl + 1), __ATOMIC_RELAXED,
                           __HIP_MEMORY_SCOPE_AGENT);
      if (w == 0) {
        const unsigned e = (unsigned)(tl + 1);
        while (true) {
          unsigned v = __hip_atomic_load(grp + (l & 31), __ATOMIC_RELAXED,
                                         __HIP_MEMORY_SCOPE_AGENT);
          if (__all((int)(v >= e))) break;
          __builtin_amdgcn_s_sleep(1);
        }
        // acquire: emits L1+L2 invalidate (1 wg/CU -> covers all 8 waves)
        (void)__hip_atomic_load(grp + (l & 31), __ATOMIC_ACQUIRE,
                                __HIP_MEMORY_SCOPE_AGENT);
      }
      __syncthreads();  // S0: release — caches clean, producers at tl+1
    }
    X0 = N0; X1 = N1; X2 = N2; X3 = N3;
  }
  Cst[sa] = ca; Hst[sa] = ha;
  Cst[sa + 1] = cb; Hst[sa + 1] = hb;
}

// ---------------- emissions (unchanged) ----------------
__global__ __launch_bounds__(256) void emis_kernel(
    const unsigned short* __restrict__ outbf, const float* __restrict__ Wout,
    const float* __restrict__ bout, float* __restrict__ emis) {
  __shared__ float red[64][25][4];
  int tid = threadIdx.x;
  int p = tid >> 6, rr = tid & 63;
  int r = blockIdx.x * 64 + rr;
  int b = r >> 9, t = r & 511;
  int dir = p >> 1;
  int jq = (p & 1) * 256;
  const unsigned short* hp =
      outbf + (size_t)dir * 16777216 + ((size_t)b * 512 + t) * 512 + jq;
  float acc[24];
#pragma unroll
  for (int i = 0; i < 24; ++i) acc[i] = 0.f;
  for (int kc = 0; kc < 32; ++kc) {
    uint4 vh = *(const uint4*)(hp + kc * 8);
    unsigned uhv[4] = {vh.x, vh.y, vh.z, vh.w};
    float f[8];
#pragma unroll
    for (int z = 0; z < 4; ++z) {
      f[2 * z] = bf2f((unsigned short)(uhv[z] & 0xffff));
      f[2 * z + 1] = bf2f((unsigned short)(uhv[z] >> 16));
    }
    const float* wbase = Wout + dir * 512 + jq + kc * 8;
#pragma unroll
    for (int nn = 0; nn < 24; ++nn) {
      const float* wr = wbase + nn * 1024;
      float4 w0 = *(const float4*)(wr);
      float4 w1 = *(const float4*)(wr + 4);
      acc[nn] += f[0] * w0.x + f[1] * w0.y + f[2] * w0.z + f[3] * w0.w +
                 f[4] * w1.x + f[5] * w1.y + f[6] * w1.z + f[7] * w1.w;
    }
  }
#pragma unroll
  for (int nn = 0; nn < 24; ++nn) red[rr][nn][p] = acc[nn];
  __syncthreads();
#pragma unroll
  for (int oi = 0; oi < 6; ++oi) {
    int idx = tid + 256 * oi;
    int rr2 = idx / 24, n2 = idx % 24;
    float v = red[rr2][n2][0] + red[rr2][n2][1] + red[rr2][n2][2] +
              red[rr2][n2][3] + bout[n2];
    emis[((size_t)blockIdx.x * 64 + rr2) * 24 + n2] = v;
  }
}

// ---------------- Viterbi (unchanged) ----------------
__global__ __launch_bounds__(64) void viterbi_kernel(
    const float* __restrict__ emis, const int* __restrict__ length,
    const float* __restrict__ trans, float* __restrict__ out) {
  __shared__ float eb[12288];
  __shared__ float tr[576];
  __shared__ unsigned char bp[512 * 24];
  __shared__ unsigned char seq[512];
  int b = blockIdx.x, l = threadIdx.x;
  const float* ebg = emis + (size_t)b * 12288;
  for (int i = l * 4; i < 12288; i += 256)
    *(float4*)(eb + i) = *(const float4*)(ebg + i);
  for (int i = l; i < 576; i += 64) tr[i] = trans[i];
  __syncthreads();
  int lc = (l < 24) ? l : 0;
  float tcol[24];
#pragma unroll
  for (int p = 0; p < 24; ++p) tcol[p] = tr[p * 24 + lc];
  int len = length[b];
  float alpha = (l < 24) ? eb[lc] + tr[22 * 24 + lc] : -3e38f;
  for (int t = 1; t < 512; ++t) {
    float mx = -3e38f;
    int arg = 0;
#pragma unroll
    for (int p = 0; p < 24; ++p) {
      float v = __shfl(alpha, p) + tcol[p];
      if (v > mx) { mx = v; arg = p; }
    }
    if (l < 24) {
      bp[t * 24 + l] = (unsigned char)arg;
      if (t < len) alpha = mx + eb[t * 24 + l];
    }
  }
  float fin = (l < 24) ? alpha + tr[lc * 24 + 23] : -3e38f;
  float best = -3e38f;
  int cur = 0;
  for (int p = 0; p < 24; ++p) {
    float v = __shfl(fin, p);
    if (v > best) { best = v; cur = p; }
  }
  int last = len - 1;
  if (l == 0) {
    out[b] = best;
    int c = cur;
    for (int t = 511; t >= 0; --t) {
      seq[t] = (unsigned char)c;
      if (t >= 1 && t <= last) c = bp[t * 24 + c];
    }
  }
  __syncthreads();
  for (int i = l; i < 512; i += 64) out[64 + b * 512 + i] = (float)seq[i];
}

// ---------------- host ----------------
extern "C" void kernel_launch(void* const* d_in, const int* in_sizes, int n_in,
                              void* d_out, int out_size, void* d_ws, size_t ws_size,
                              hipStream_t stream) {
  const float* X = (const float*)d_in[0];
  const int* length = (const int*)d_in[2];
  const float* Wih_f = (const float*)d_in[3];
  const float* Whh_f = (const float*)d_in[4];
  const float* b_f = (const float*)d_in[5];
  const float* Wih_b = (const float*)d_in[6];
  const float* Whh_b = (const float*)d_in[7];
  const float* b_b = (const float*)d_in[8];
  const float* Wout = (const float*)d_in[9];
  const float* bout = (const float*)d_in[10];
  const float* trans = (const float*)d_in[11];

  char* ws = (char*)d_ws;
  unsigned short* whh_bf = (unsigned short*)(ws + O_WHHB);
  unsigned short* wih_bf = (unsigned short*)(ws + O_WIHB);
  unsigned short* xb = (unsigned short*)(ws + O_XB);
  unsigned short* outbf = (unsigned short*)(ws + O_OUT);
  unsigned long long* hx = (unsigned long long*)(ws + O_HX);
  float* Hbuf = (float*)(ws + O_HF);
  float* Cbuf = (float*)(ws + O_CF);
  float* emis = (float*)(ws + O_EMIS);
  unsigned* bar = (unsigned*)(ws + O_BAR);
  unsigned short* xp = (unsigned short*)(ws + O_XP);

  int Tc = 2;
  const int cands[9] = {512, 256, 128, 64, 32, 16, 8, 4, 2};
  for (int i = 0; i < 9; ++i) {
    if (O_XP + (size_t)cands[i] * 524288 <= ws_size) { Tc = cands[i]; break; }
  }
  int nch = T_ / Tc;

  hipMemsetAsync(ws + O_OUT, 0, SZ_OUT, stream);
  hipMemsetAsync(ws + O_HX, 0, SZ_HX, stream);

  cast_bf<<<1024, 256, 0, stream>>>(Whh_f, whh_bf, 1048576);
  cast_bf<<<1024, 256, 0, stream>>>(Whh_b, whh_bf + 1048576, 1048576);
  cast_bf<<<1024, 256, 0, stream>>>(Wih_f, wih_bf, 1048576);
  cast_bf<<<1024, 256, 0, stream>>>(Wih_b, wih_bf + 1048576, 1048576);
  cast_bf<<<4096, 256, 0, stream>>>(X, xb, 16777216);

  for (int ch = 0; ch < nch; ++ch) {
    int t0 = ch * Tc;
    xp_gemm<<<dim3(Tc * 64 / 128, 16, 2), 256, 0, stream>>>(
        xb, wih_bf, b_f, b_b, length, xp, t0, Tc);
    hipMemsetAsync(bar, 0, 2048, stream);
    lstm_persist<<<64, 512, 0, stream>>>(whh_bf, hx, xp, length, Cbuf, Hbuf,
                                         outbf, bar, t0, Tc);
  }
  emis_kernel<<<512, 256, 0, stream>>>(outbf, Wout, bout, emis);
  viterbi_kernel<<<64, 64, 0, stream>>>(emis, length, trans, (float*)d_out);
}